// Round 1
// baseline (2007.662 us; speedup 1.0000x reference)
//
#include <hip/hip_runtime.h>

// Problem constants (match reference)
#define N_NODES 100000
#define P_PAIRS 3200000
#define IN_F    19
#define OUT_F   64
#define BN_EPS  1e-5f
#define SLOPE   0.01f

// ---------------------------------------------------------------------------
// K1: xw = x @ W_conv   (res is recomputed later in k_final; here only xw)
// one wave per node row, lane = output channel
// ---------------------------------------------------------------------------
__global__ __launch_bounds__(256) void k_input_gemm(
    const float* __restrict__ x, const float* __restrict__ Wc,
    float* __restrict__ xw)
{
    __shared__ float sWc[IN_F * OUT_F];
    for (int i = threadIdx.x; i < IN_F * OUT_F; i += 256) sWc[i] = Wc[i];
    __syncthreads();
    int wave = threadIdx.x >> 6;
    int lane = threadIdx.x & 63;
    int n = blockIdx.x * 4 + wave;           // N divisible by 4
    const float* xr = x + n * IN_F;
    float acc = 0.f;
    #pragma unroll
    for (int k = 0; k < IN_F; ++k) {
        float xv = xr[k];                    // broadcast load, L1-cached
        acc += xv * sWc[k * OUT_F + lane];
    }
    xw[n * OUT_F + lane] = acc;
}

// ---------------------------------------------------------------------------
// K2: degree counts D[node], B[edge] via scalar atomics (exact in f32)
// ---------------------------------------------------------------------------
__global__ __launch_bounds__(256) void k_degrees(
    const int* __restrict__ ni, const int* __restrict__ ei,
    float* __restrict__ D, float* __restrict__ B)
{
    int p = blockIdx.x * 256 + threadIdx.x;  // grid sized exactly P/256
    atomicAdd(&D[ni[p]], 1.0f);
    atomicAdd(&B[ei[p]], 1.0f);
}

// ---------------------------------------------------------------------------
// K3: edge_feat[e] += xw[n]  — one wave per pair, lane = channel
// ---------------------------------------------------------------------------
__global__ __launch_bounds__(256) void k_scatter_edge(
    const int* __restrict__ ni, const int* __restrict__ ei,
    const float* __restrict__ xw, float* __restrict__ ef)
{
    int wave = threadIdx.x >> 6;
    int lane = threadIdx.x & 63;
    int p = blockIdx.x * 4 + wave;           // grid sized exactly P/4
    int n = ni[p];
    int e = ei[p];
    float v = xw[n * OUT_F + lane];
    atomicAdd(&ef[e * OUT_F + lane], v);
}

// ---------------------------------------------------------------------------
// K4: out_agg[n] += edge_feat[e] * B_inv[e]
// ---------------------------------------------------------------------------
__global__ __launch_bounds__(256) void k_scatter_node(
    const int* __restrict__ ni, const int* __restrict__ ei,
    const float* __restrict__ ef, const float* __restrict__ B,
    float* __restrict__ oa)
{
    int wave = threadIdx.x >> 6;
    int lane = threadIdx.x & 63;
    int p = blockIdx.x * 4 + wave;
    int n = ni[p];
    int e = ei[p];
    float b = B[e];
    float binv = (b > 0.f) ? (1.f / b) : 0.f;
    float v = ef[e * OUT_F + lane] * binv;
    atomicAdd(&oa[n * OUT_F + lane], v);
}

// ---------------------------------------------------------------------------
// K5: conv = oa * D_inv + b_conv ; h = conv @ W_mlp + b_mlp  (h -> d_out)
//     + per-channel BN partial sums (sum, sumsq) via per-wave accum + atomics
// one wave per row (grid-stride), lane = channel; row broadcast via __shfl
// ---------------------------------------------------------------------------
__global__ __launch_bounds__(256) void k_mlp(
    const float* __restrict__ oa, const float* __restrict__ D,
    const float* __restrict__ bconv, const float* __restrict__ Wm,
    const float* __restrict__ bm, float* __restrict__ h,
    float* __restrict__ bnsum)
{
    __shared__ float sW[OUT_F * OUT_F];
    for (int i = threadIdx.x; i < OUT_F * OUT_F; i += 256) sW[i] = Wm[i];
    __syncthreads();
    int lane = threadIdx.x & 63;
    int gwave = (blockIdx.x * 256 + threadIdx.x) >> 6;
    int nwaves = gridDim.x * 4;
    float bmc = bm[lane];
    float bcc = bconv[lane];
    float s = 0.f, s2 = 0.f;
    for (int n = gwave; n < N_NODES; n += nwaves) {
        float dv = D[n];
        float dinv = (dv > 0.f) ? (1.f / dv) : 0.f;
        float cv = oa[n * OUT_F + lane] * dinv + bcc;
        float acc = bmc;
        #pragma unroll
        for (int k = 0; k < OUT_F; ++k) {
            acc += __shfl(cv, k, 64) * sW[k * OUT_F + lane];
        }
        h[n * OUT_F + lane] = acc;
        s  += acc;
        s2 += acc * acc;
    }
    atomicAdd(&bnsum[lane], s);
    atomicAdd(&bnsum[64 + lane], s2);
}

// ---------------------------------------------------------------------------
// K6: BN normalize + LeakyReLU + residual (x @ W_res + b_res) + LeakyReLU
// one wave per row; h read from d_out, result written in place
// ---------------------------------------------------------------------------
__global__ __launch_bounds__(256) void k_final(
    const float* __restrict__ x, const float* __restrict__ Wr,
    const float* __restrict__ br, const float* __restrict__ bnsum,
    const float* __restrict__ gamma, const float* __restrict__ beta,
    float* __restrict__ out)
{
    __shared__ float sWr[IN_F * OUT_F];
    for (int i = threadIdx.x; i < IN_F * OUT_F; i += 256) sWr[i] = Wr[i];
    __syncthreads();
    int wave = threadIdx.x >> 6;
    int lane = threadIdx.x & 63;
    int n = blockIdx.x * 4 + wave;
    const float inv_n = 1.f / (float)N_NODES;
    float mean = bnsum[lane] * inv_n;
    float var  = bnsum[64 + lane] * inv_n - mean * mean;
    float rstd = rsqrtf(var + BN_EPS);
    float g = gamma[lane], bt = beta[lane];

    // residual: x[n] @ W_res + b_res
    const float* xr = x + n * IN_F;
    float r = br[lane];
    #pragma unroll
    for (int k = 0; k < IN_F; ++k) {
        r += xr[k] * sWr[k * OUT_F + lane];
    }

    float hv = out[n * OUT_F + lane];
    float a = g * (hv - mean) * rstd + bt;
    a = (a >= 0.f) ? a : SLOPE * a;
    float y = a + r;
    out[n * OUT_F + lane] = (y >= 0.f) ? y : SLOPE * y;
}

// ---------------------------------------------------------------------------
extern "C" void kernel_launch(void* const* d_in, const int* in_sizes, int n_in,
                              void* d_out, int out_size, void* d_ws, size_t ws_size,
                              hipStream_t stream) {
    const float* x     = (const float*)d_in[0];
    const int*   hidx  = (const int*)d_in[1];      // [2, P] int
    const int*   ni    = hidx;                     // row 0: node idx
    const int*   ei    = hidx + P_PAIRS;           // row 1: edge idx
    const float* Wc    = (const float*)d_in[2];
    const float* bc    = (const float*)d_in[3];
    const float* Wm    = (const float*)d_in[4];
    const float* bm    = (const float*)d_in[5];
    const float* gamma = (const float*)d_in[6];
    const float* beta  = (const float*)d_in[7];
    const float* Wr    = (const float*)d_in[8];
    const float* br    = (const float*)d_in[9];
    float* out = (float*)d_out;

    // workspace layout (floats):
    //  [ef N*64][D N][B N][bn 128][buf N*64]   buf = xw, later reused as oa
    float* ws  = (float*)d_ws;
    float* ef  = ws;
    float* Dd  = ef + N_NODES * OUT_F;
    float* Bd  = Dd + N_NODES;
    float* bns = Bd + N_NODES;
    float* buf = bns + 128;                        // xw / oa (aliased)

    // zero ef + D + B + bn in one contiguous memset
    size_t z1 = (size_t)(N_NODES * OUT_F + 2 * N_NODES + 128) * sizeof(float);
    hipMemsetAsync(ef, 0, z1, stream);

    k_input_gemm<<<N_NODES / 4, 256, 0, stream>>>(x, Wc, buf);
    k_degrees<<<P_PAIRS / 256, 256, 0, stream>>>(ni, ei, Dd, Bd);
    k_scatter_edge<<<P_PAIRS / 4, 256, 0, stream>>>(ni, ei, buf, ef);

    // buf (xw) is dead now; reuse as node aggregation accumulator
    hipMemsetAsync(buf, 0, (size_t)N_NODES * OUT_F * sizeof(float), stream);
    k_scatter_node<<<P_PAIRS / 4, 256, 0, stream>>>(ni, ei, ef, Bd, buf);

    // h staged in d_out
    k_mlp<<<1024, 256, 0, stream>>>(buf, Dd, bc, Wm, bm, out, bns);
    k_final<<<N_NODES / 4, 256, 0, stream>>>(x, Wr, br, bns, gamma, beta, out);
}

// Round 2
// 1595.820 us; speedup vs baseline: 1.2581x; 1.2581x over previous
//
#include <hip/hip_runtime.h>

#define N_NODES 100000
#define P_PAIRS 3200000
#define IN_F    19
#define OUT_F   64
#define BN_EPS  1e-5f
#define SLOPE   0.01f
#define SCAN_T  1024
#define CHUNK   98      // ceil(N_NODES / SCAN_T)

// ---------------------------------------------------------------------------
// K1: xw = x @ W_conv  (staged into d_out; dead before h lands there)
// one wave per node row, lane = output channel
// ---------------------------------------------------------------------------
__global__ __launch_bounds__(256) void k_input_gemm(
    const float* __restrict__ x, const float* __restrict__ Wc,
    float* __restrict__ xw)
{
    __shared__ float sWc[IN_F * OUT_F];
    for (int i = threadIdx.x; i < IN_F * OUT_F; i += 256) sWc[i] = Wc[i];
    __syncthreads();
    int wave = threadIdx.x >> 6;
    int lane = threadIdx.x & 63;
    int n = blockIdx.x * 4 + wave;           // N divisible by 4
    const float* xr = x + n * IN_F;
    float acc = 0.f;
    #pragma unroll
    for (int k = 0; k < IN_F; ++k) acc += xr[k] * sWc[k * OUT_F + lane];
    xw[n * OUT_F + lane] = acc;
}

// ---------------------------------------------------------------------------
// K2: int histograms: cntD[node], cntB[edge]
// ---------------------------------------------------------------------------
__global__ __launch_bounds__(256) void k_hist(
    const int* __restrict__ ni, const int* __restrict__ ei,
    int* __restrict__ cntD, int* __restrict__ cntB)
{
    int p = blockIdx.x * 256 + threadIdx.x;  // grid exactly P/256
    atomicAdd(&cntD[ni[p]], 1);
    atomicAdd(&cntB[ei[p]], 1);
}

// ---------------------------------------------------------------------------
// K3: exclusive scan of both histograms (block 0: cntB->offE, block 1: cntD->offN)
// ---------------------------------------------------------------------------
__global__ __launch_bounds__(SCAN_T) void k_scan(
    const int* __restrict__ cntB, const int* __restrict__ cntD,
    int* __restrict__ offE, int* __restrict__ offN)
{
    __shared__ int s[SCAN_T];
    const int* src = (blockIdx.x == 0) ? cntB : cntD;
    int* dst       = (blockIdx.x == 0) ? offE : offN;
    int t = threadIdx.x;
    int base = t * CHUNK;
    int sum = 0;
    for (int i = 0; i < CHUNK; ++i) {
        int idx = base + i;
        sum += (idx < N_NODES) ? src[idx] : 0;
    }
    s[t] = sum;
    __syncthreads();
    for (int off = 1; off < SCAN_T; off <<= 1) {
        int tmp = 0;
        if (t >= off) tmp = s[t - off];
        __syncthreads();
        if (t >= off) s[t] += tmp;
        __syncthreads();
    }
    int run = (t == 0) ? 0 : s[t - 1];
    for (int i = 0; i < CHUNK; ++i) {
        int idx = base + i;
        if (idx < N_NODES) { dst[idx] = run; run += src[idx]; }
    }
}

// ---------------------------------------------------------------------------
// K4: counting-sort build: adj[pos] = val, grouped by key.
// Bumps off[] so that afterwards off[k] == segment END for key k.
// ---------------------------------------------------------------------------
__global__ __launch_bounds__(256) void k_build(
    const int* __restrict__ key, const int* __restrict__ val,
    int* __restrict__ off, int* __restrict__ adj)
{
    int p = blockIdx.x * 256 + threadIdx.x;
    int k = key[p];
    int v = val[p];
    int pos = atomicAdd(&off[k], 1);
    adj[pos] = v;
}

// ---------------------------------------------------------------------------
// K5: per-edge segmented gather-reduce: ef[e] = B_inv * sum xw[n in edge]
// one wave per edge, lane = channel; 4-deep unroll for load ILP
// ---------------------------------------------------------------------------
__global__ __launch_bounds__(256) void k_edge(
    const int* __restrict__ adj, const int* __restrict__ offE,
    const int* __restrict__ cntB, const float* __restrict__ xw,
    float* __restrict__ ef)
{
    int wave = threadIdx.x >> 6;
    int lane = threadIdx.x & 63;
    int e = blockIdx.x * 4 + wave;           // grid exactly N/4
    int len = cntB[e];
    int end = offE[e];                        // post-build: segment end
    int i = end - len;
    float a0 = 0.f, a1 = 0.f, a2 = 0.f, a3 = 0.f;
    for (; i + 4 <= end; i += 4) {
        int n0 = adj[i], n1 = adj[i + 1], n2 = adj[i + 2], n3 = adj[i + 3];
        a0 += xw[n0 * OUT_F + lane];
        a1 += xw[n1 * OUT_F + lane];
        a2 += xw[n2 * OUT_F + lane];
        a3 += xw[n3 * OUT_F + lane];
    }
    for (; i < end; ++i) a0 += xw[adj[i] * OUT_F + lane];
    float binv = (len > 0) ? 1.f / (float)len : 0.f;
    ef[e * OUT_F + lane] = ((a0 + a1) + (a2 + a3)) * binv;
}

// ---------------------------------------------------------------------------
// K6: per-node gather-reduce + conv bias + 64x64 MLP GEMM (shfl) + BN partials
// grid-stride waves; h -> d_out
// ---------------------------------------------------------------------------
__global__ __launch_bounds__(256) void k_node_mlp(
    const int* __restrict__ adj, const int* __restrict__ offN,
    const int* __restrict__ cntD, const float* __restrict__ ef,
    const float* __restrict__ bconv, const float* __restrict__ Wm,
    const float* __restrict__ bm, float* __restrict__ h,
    float* __restrict__ bns)
{
    __shared__ float sW[OUT_F * OUT_F];
    for (int i = threadIdx.x; i < OUT_F * OUT_F; i += 256) sW[i] = Wm[i];
    __syncthreads();
    int lane = threadIdx.x & 63;
    int gw = (blockIdx.x * 256 + threadIdx.x) >> 6;
    int nw = gridDim.x * 4;
    float bmc = bm[lane];
    float bcc = bconv[lane];
    float s = 0.f, s2 = 0.f;
    for (int n = gw; n < N_NODES; n += nw) {
        int len = cntD[n];
        int end = offN[n];
        int i = end - len;
        float a0 = 0.f, a1 = 0.f, a2 = 0.f, a3 = 0.f;
        for (; i + 4 <= end; i += 4) {
            int e0 = adj[i], e1 = adj[i + 1], e2 = adj[i + 2], e3 = adj[i + 3];
            a0 += ef[e0 * OUT_F + lane];
            a1 += ef[e1 * OUT_F + lane];
            a2 += ef[e2 * OUT_F + lane];
            a3 += ef[e3 * OUT_F + lane];
        }
        for (; i < end; ++i) a0 += ef[adj[i] * OUT_F + lane];
        float dinv = (len > 0) ? 1.f / (float)len : 0.f;
        float cv = ((a0 + a1) + (a2 + a3)) * dinv + bcc;
        float acc = bmc;
        #pragma unroll
        for (int k = 0; k < OUT_F; ++k)
            acc += __shfl(cv, k, 64) * sW[k * OUT_F + lane];
        h[n * OUT_F + lane] = acc;
        s  += acc;
        s2 += acc * acc;
    }
    atomicAdd(&bns[lane], s);
    atomicAdd(&bns[64 + lane], s2);
}

// ---------------------------------------------------------------------------
// K7: BN normalize + LeakyReLU + residual (x @ W_res + b_res) + LeakyReLU
// ---------------------------------------------------------------------------
__global__ __launch_bounds__(256) void k_final(
    const float* __restrict__ x, const float* __restrict__ Wr,
    const float* __restrict__ br, const float* __restrict__ bns,
    const float* __restrict__ gamma, const float* __restrict__ beta,
    float* __restrict__ out)
{
    __shared__ float sWr[IN_F * OUT_F];
    for (int i = threadIdx.x; i < IN_F * OUT_F; i += 256) sWr[i] = Wr[i];
    __syncthreads();
    int wave = threadIdx.x >> 6;
    int lane = threadIdx.x & 63;
    int n = blockIdx.x * 4 + wave;
    const float inv_n = 1.f / (float)N_NODES;
    float mean = bns[lane] * inv_n;
    float var  = bns[64 + lane] * inv_n - mean * mean;
    float rstd = rsqrtf(var + BN_EPS);
    float g = gamma[lane], bt = beta[lane];

    const float* xr = x + n * IN_F;
    float r = br[lane];
    #pragma unroll
    for (int k = 0; k < IN_F; ++k) r += xr[k] * sWr[k * OUT_F + lane];

    float hv = out[n * OUT_F + lane];
    float a = g * (hv - mean) * rstd + bt;
    a = (a >= 0.f) ? a : SLOPE * a;
    float y = a + r;
    out[n * OUT_F + lane] = (y >= 0.f) ? y : SLOPE * y;
}

// ---------------------------------------------------------------------------
extern "C" void kernel_launch(void* const* d_in, const int* in_sizes, int n_in,
                              void* d_out, int out_size, void* d_ws, size_t ws_size,
                              hipStream_t stream) {
    const float* x     = (const float*)d_in[0];
    const int*   hidx  = (const int*)d_in[1];
    const int*   ni    = hidx;               // row 0: node idx
    const int*   ei    = hidx + P_PAIRS;     // row 1: edge idx
    const float* Wc    = (const float*)d_in[2];
    const float* bc    = (const float*)d_in[3];
    const float* Wm    = (const float*)d_in[4];
    const float* bm    = (const float*)d_in[5];
    const float* gamma = (const float*)d_in[6];
    const float* beta  = (const float*)d_in[7];
    const float* Wr    = (const float*)d_in[8];
    const float* br    = (const float*)d_in[9];
    float* out = (float*)d_out;

    // workspace layout (ints/floats, ~40 MB):
    // [cntB N][cntD N][bns 128][offE N][offN N][adj P][ef N*64]
    int*   cntB = (int*)d_ws;
    int*   cntD = cntB + N_NODES;
    float* bns  = (float*)(cntD + N_NODES);
    int*   offE = (int*)(bns + 128);
    int*   offN = offE + N_NODES;
    int*   adj  = offN + N_NODES;
    float* ef   = (float*)(adj + P_PAIRS);

    // zero cntB + cntD + bns (contiguous)
    hipMemsetAsync(cntB, 0, (size_t)(2 * N_NODES + 128) * sizeof(int), stream);

    float* xw = out;  // stage xw in d_out; dead before h is written there

    k_input_gemm<<<N_NODES / 4, 256, 0, stream>>>(x, Wc, xw);
    k_hist<<<P_PAIRS / 256, 256, 0, stream>>>(ni, ei, cntD, cntB);
    k_scan<<<2, SCAN_T, 0, stream>>>(cntB, cntD, offE, offN);

    // edge-side CSR: adj = node ids grouped by edge
    k_build<<<P_PAIRS / 256, 256, 0, stream>>>(ei, ni, offE, adj);
    k_edge<<<N_NODES / 4, 256, 0, stream>>>(adj, offE, cntB, xw, ef);

    // node-side CSR (reuse adj): adj = edge ids grouped by node
    k_build<<<P_PAIRS / 256, 256, 0, stream>>>(ni, ei, offN, adj);
    k_node_mlp<<<2048, 256, 0, stream>>>(adj, offN, cntD, ef, bc, Wm, bm, out, bns);

    k_final<<<N_NODES / 4, 256, 0, stream>>>(x, Wr, br, bns, gamma, beta, out);
}

// Round 3
// 1490.942 us; speedup vs baseline: 1.3466x; 1.0703x over previous
//
#include <hip/hip_runtime.h>

#define N_NODES 100000
#define P_PAIRS 3200000
#define IN_F    19
#define OUT_F   64
#define BN_EPS  1e-5f
#define SLOPE   0.01f
#define SCAN_T  1024
#define CHUNK   98      // ceil(N_NODES / SCAN_T)

typedef __attribute__((ext_vector_type(8))) unsigned short u16x8;

__device__ __forceinline__ float bf2f(unsigned short h) {
    return __uint_as_float(((unsigned)h) << 16);
}
__device__ __forceinline__ unsigned short f2bf(float f) {
    unsigned u = __float_as_uint(f);
    return (unsigned short)((u + 0x7FFF + ((u >> 16) & 1)) >> 16);  // RNE
}

// ---------------------------------------------------------------------------
// K1: xw = x @ W_conv  -> bf16 table (staged in d_out; dead before h lands)
// one wave per node row, lane = output channel
// ---------------------------------------------------------------------------
__global__ __launch_bounds__(256) void k_input_gemm(
    const float* __restrict__ x, const float* __restrict__ Wc,
    unsigned short* __restrict__ xwb)
{
    __shared__ float sWc[IN_F * OUT_F];
    for (int i = threadIdx.x; i < IN_F * OUT_F; i += 256) sWc[i] = Wc[i];
    __syncthreads();
    int wave = threadIdx.x >> 6;
    int lane = threadIdx.x & 63;
    int n = blockIdx.x * 4 + wave;           // N divisible by 4
    const float* xr = x + n * IN_F;
    float acc = 0.f;
    #pragma unroll
    for (int k = 0; k < IN_F; ++k) acc += xr[k] * sWc[k * OUT_F + lane];
    xwb[(size_t)n * OUT_F + lane] = f2bf(acc);
}

// ---------------------------------------------------------------------------
// K2: int histograms: cntD[node], cntB[edge]
// ---------------------------------------------------------------------------
__global__ __launch_bounds__(256) void k_hist(
    const int* __restrict__ ni, const int* __restrict__ ei,
    int* __restrict__ cntD, int* __restrict__ cntB)
{
    int p = blockIdx.x * 256 + threadIdx.x;  // grid exactly P/256
    atomicAdd(&cntD[ni[p]], 1);
    atomicAdd(&cntB[ei[p]], 1);
}

// ---------------------------------------------------------------------------
// K3: exclusive scan of both histograms
// ---------------------------------------------------------------------------
__global__ __launch_bounds__(SCAN_T) void k_scan(
    const int* __restrict__ cntB, const int* __restrict__ cntD,
    int* __restrict__ offE, int* __restrict__ offN)
{
    __shared__ int s[SCAN_T];
    const int* src = (blockIdx.x == 0) ? cntB : cntD;
    int* dst       = (blockIdx.x == 0) ? offE : offN;
    int t = threadIdx.x;
    int base = t * CHUNK;
    int sum = 0;
    for (int i = 0; i < CHUNK; ++i) {
        int idx = base + i;
        sum += (idx < N_NODES) ? src[idx] : 0;
    }
    s[t] = sum;
    __syncthreads();
    for (int off = 1; off < SCAN_T; off <<= 1) {
        int tmp = 0;
        if (t >= off) tmp = s[t - off];
        __syncthreads();
        if (t >= off) s[t] += tmp;
        __syncthreads();
    }
    int run = (t == 0) ? 0 : s[t - 1];
    for (int i = 0; i < CHUNK; ++i) {
        int idx = base + i;
        if (idx < N_NODES) { dst[idx] = run; run += src[idx]; }
    }
}

// ---------------------------------------------------------------------------
// K4: combined counting-sort build for BOTH sides in one pass over pairs.
// Afterwards off[k] == segment END for key k.
// ---------------------------------------------------------------------------
__global__ __launch_bounds__(256) void k_build_both(
    const int* __restrict__ ni, const int* __restrict__ ei,
    int* __restrict__ offE, int* __restrict__ offN,
    int* __restrict__ adjE, int* __restrict__ adjN)
{
    int p = blockIdx.x * 256 + threadIdx.x;
    int n = ni[p];
    int e = ei[p];
    int posE = atomicAdd(&offE[e], 1);
    adjE[posE] = n;
    int posN = atomicAdd(&offN[n], 1);
    adjN[posN] = e;
}

// ---------------------------------------------------------------------------
// K5: per-edge gather-reduce: ef[e] = B_inv * sum xw[n in edge]   (bf16 I/O)
// wave per edge; lane = (row-slot sub 0..7, chan-group cg 0..7)
// each 16B load covers 8 channels of one row; 8 rows per instruction.
// ---------------------------------------------------------------------------
__global__ __launch_bounds__(256) void k_edge(
    const int* __restrict__ adjE, const int* __restrict__ offE,
    const int* __restrict__ cntB, const unsigned short* __restrict__ xwb,
    unsigned short* __restrict__ efb)
{
    int wave = threadIdx.x >> 6;
    int lane = threadIdx.x & 63;
    int sub = lane >> 3;
    int cg  = lane & 7;
    int e = blockIdx.x * 4 + wave;           // grid exactly N/4
    int len = cntB[e];
    int end = offE[e];
    int start = end - len;

    float acc[8];
    #pragma unroll
    for (int j = 0; j < 8; ++j) acc[j] = 0.f;

    int i = start + sub;
    for (; i + 8 < end; i += 16) {           // 2 rows in flight per lane
        int n0 = adjE[i];
        int n1 = adjE[i + 8];
        u16x8 v0 = *(const u16x8*)(xwb + (size_t)n0 * OUT_F + cg * 8);
        u16x8 v1 = *(const u16x8*)(xwb + (size_t)n1 * OUT_F + cg * 8);
        #pragma unroll
        for (int j = 0; j < 8; ++j) acc[j] += bf2f(v0[j]);
        #pragma unroll
        for (int j = 0; j < 8; ++j) acc[j] += bf2f(v1[j]);
    }
    if (i < end) {
        int n0 = adjE[i];
        u16x8 v0 = *(const u16x8*)(xwb + (size_t)n0 * OUT_F + cg * 8);
        #pragma unroll
        for (int j = 0; j < 8; ++j) acc[j] += bf2f(v0[j]);
    }

    #pragma unroll
    for (int off = 8; off < 64; off <<= 1) {
        #pragma unroll
        for (int j = 0; j < 8; ++j) acc[j] += __shfl_xor(acc[j], off, 64);
    }

    float binv = (len > 0) ? 1.f / (float)len : 0.f;
    if (sub == 0) {
        u16x8 o;
        #pragma unroll
        for (int j = 0; j < 8; ++j) o[j] = f2bf(acc[j] * binv);
        *(u16x8*)(efb + (size_t)e * OUT_F + cg * 8) = o;
    }
}

// ---------------------------------------------------------------------------
// K6: per-node gather-reduce (bf16 ef) + conv bias + 64x64 MLP GEMM (shfl)
//     + BN partials. grid-stride waves; h (f32) -> d_out.
// ---------------------------------------------------------------------------
__global__ __launch_bounds__(256) void k_node_mlp(
    const int* __restrict__ adjN, const int* __restrict__ offN,
    const int* __restrict__ cntD, const unsigned short* __restrict__ efb,
    const float* __restrict__ bconv, const float* __restrict__ Wm,
    const float* __restrict__ bm, float* __restrict__ h,
    float* __restrict__ bns)
{
    __shared__ float sW[OUT_F * OUT_F];
    for (int t = threadIdx.x; t < OUT_F * OUT_F; t += 256) sW[t] = Wm[t];
    __syncthreads();
    int lane = threadIdx.x & 63;
    int sub = lane >> 3;
    int cg  = lane & 7;
    float bcv[8];
    #pragma unroll
    for (int j = 0; j < 8; ++j) bcv[j] = bconv[cg * 8 + j];
    float bmc = bm[lane];

    int gw = (blockIdx.x * 256 + threadIdx.x) >> 6;
    int nw = gridDim.x * 4;
    float s = 0.f, s2 = 0.f;

    for (int n = gw; n < N_NODES; n += nw) {
        int len = cntD[n];
        int end = offN[n];
        int start = end - len;

        float acc[8];
        #pragma unroll
        for (int j = 0; j < 8; ++j) acc[j] = 0.f;

        int i = start + sub;
        for (; i + 8 < end; i += 16) {
            int e0 = adjN[i];
            int e1 = adjN[i + 8];
            u16x8 v0 = *(const u16x8*)(efb + (size_t)e0 * OUT_F + cg * 8);
            u16x8 v1 = *(const u16x8*)(efb + (size_t)e1 * OUT_F + cg * 8);
            #pragma unroll
            for (int j = 0; j < 8; ++j) acc[j] += bf2f(v0[j]);
            #pragma unroll
            for (int j = 0; j < 8; ++j) acc[j] += bf2f(v1[j]);
        }
        if (i < end) {
            int e0 = adjN[i];
            u16x8 v0 = *(const u16x8*)(efb + (size_t)e0 * OUT_F + cg * 8);
            #pragma unroll
            for (int j = 0; j < 8; ++j) acc[j] += bf2f(v0[j]);
        }

        #pragma unroll
        for (int off = 8; off < 64; off <<= 1) {
            #pragma unroll
            for (int j = 0; j < 8; ++j) acc[j] += __shfl_xor(acc[j], off, 64);
        }

        float dinv = (len > 0) ? 1.f / (float)len : 0.f;
        float cvv[8];
        #pragma unroll
        for (int j = 0; j < 8; ++j) cvv[j] = acc[j] * dinv + bcv[j];

        float a = bmc;
        #pragma unroll
        for (int c = 0; c < OUT_F; ++c)
            a += __shfl(cvv[c & 7], c >> 3, 64) * sW[c * OUT_F + lane];

        h[(size_t)n * OUT_F + lane] = a;
        s  += a;
        s2 += a * a;
    }
    atomicAdd(&bns[lane], s);
    atomicAdd(&bns[64 + lane], s2);
}

// ---------------------------------------------------------------------------
// K7: BN normalize + LeakyReLU + residual (x @ W_res + b_res) + LeakyReLU
// ---------------------------------------------------------------------------
__global__ __launch_bounds__(256) void k_final(
    const float* __restrict__ x, const float* __restrict__ Wr,
    const float* __restrict__ br, const float* __restrict__ bns,
    const float* __restrict__ gamma, const float* __restrict__ beta,
    float* __restrict__ out)
{
    __shared__ float sWr[IN_F * OUT_F];
    for (int i = threadIdx.x; i < IN_F * OUT_F; i += 256) sWr[i] = Wr[i];
    __syncthreads();
    int wave = threadIdx.x >> 6;
    int lane = threadIdx.x & 63;
    int n = blockIdx.x * 4 + wave;
    const float inv_n = 1.f / (float)N_NODES;
    float mean = bns[lane] * inv_n;
    float var  = bns[64 + lane] * inv_n - mean * mean;
    float rstd = rsqrtf(var + BN_EPS);
    float g = gamma[lane], bt = beta[lane];

    const float* xr = x + n * IN_F;
    float r = br[lane];
    #pragma unroll
    for (int k = 0; k < IN_F; ++k) r += xr[k] * sWr[k * OUT_F + lane];

    float hv = out[(size_t)n * OUT_F + lane];
    float a = g * (hv - mean) * rstd + bt;
    a = (a >= 0.f) ? a : SLOPE * a;
    float y = a + r;
    out[(size_t)n * OUT_F + lane] = (y >= 0.f) ? y : SLOPE * y;
}

// ---------------------------------------------------------------------------
extern "C" void kernel_launch(void* const* d_in, const int* in_sizes, int n_in,
                              void* d_out, int out_size, void* d_ws, size_t ws_size,
                              hipStream_t stream) {
    const float* x     = (const float*)d_in[0];
    const int*   hidx  = (const int*)d_in[1];
    const int*   ni    = hidx;               // row 0: node idx
    const int*   ei    = hidx + P_PAIRS;     // row 1: edge idx
    const float* Wc    = (const float*)d_in[2];
    const float* bc    = (const float*)d_in[3];
    const float* Wm    = (const float*)d_in[4];
    const float* bm    = (const float*)d_in[5];
    const float* gamma = (const float*)d_in[6];
    const float* beta  = (const float*)d_in[7];
    const float* Wr    = (const float*)d_in[8];
    const float* br    = (const float*)d_in[9];
    float* out = (float*)d_out;

    // ws layout: [cntB N][cntD N][bns 128f][offE N][offN N][adjE P][adjN P][efb N*64 u16]
    // = 1.6MB + 512B + 0.8MB + 25.6MB + 12.8MB ~= 40.8MB
    int*   cntB = (int*)d_ws;
    int*   cntD = cntB + N_NODES;
    float* bns  = (float*)(cntD + N_NODES);
    int*   offE = (int*)(bns + 128);
    int*   offN = offE + N_NODES;
    int*   adjE = offN + N_NODES;
    int*   adjN = adjE + P_PAIRS;
    unsigned short* efb = (unsigned short*)(adjN + P_PAIRS);

    // xw (bf16) staged in d_out; dead before h is written there
    unsigned short* xwb = (unsigned short*)d_out;

    // zero cntB + cntD + bns (contiguous)
    hipMemsetAsync(cntB, 0, (size_t)(2 * N_NODES) * sizeof(int) + 128 * sizeof(float), stream);

    k_input_gemm<<<N_NODES / 4, 256, 0, stream>>>(x, Wc, xwb);
    k_hist<<<P_PAIRS / 256, 256, 0, stream>>>(ni, ei, cntD, cntB);
    k_scan<<<2, SCAN_T, 0, stream>>>(cntB, cntD, offE, offN);
    k_build_both<<<P_PAIRS / 256, 256, 0, stream>>>(ni, ei, offE, offN, adjE, adjN);
    k_edge<<<N_NODES / 4, 256, 0, stream>>>(adjE, offE, cntB, xwb, efb);
    k_node_mlp<<<2048, 256, 0, stream>>>(adjN, offN, cntD, efb, bc, Wm, bm, out, bns);
    k_final<<<N_NODES / 4, 256, 0, stream>>>(x, Wr, br, bns, gamma, beta, out);
}

// Round 4
// 1029.936 us; speedup vs baseline: 1.9493x; 1.4476x over previous
//
#include <hip/hip_runtime.h>

#define N_NODES 100000
#define P_PAIRS 3200000
#define IN_F    19
#define OUT_F   64
#define BN_EPS  1e-5f
#define SLOPE   0.01f
#define SCAN_T  1024
#define CHUNK   98      // ceil(N_NODES / SCAN_T)
#define BSHIFT  8       // 256 keys per bucket
#define BUCKETS 391     // ceil(N_NODES / 256)
#define CHUNK_P 6400    // pairs per phase-1 block (P / 6400 = 500 blocks)

typedef __attribute__((ext_vector_type(8))) unsigned short u16x8;

__device__ __forceinline__ float bf2f(unsigned short h) {
    return __uint_as_float(((unsigned)h) << 16);
}
__device__ __forceinline__ unsigned short f2bf(float f) {
    unsigned u = __float_as_uint(f);
    return (unsigned short)((u + 0x7FFF + ((u >> 16) & 1)) >> 16);  // RNE
}

// ---------------------------------------------------------------------------
// K1: xw = x @ W_conv  -> bf16 table (staged in d_out; dead before h lands)
// ---------------------------------------------------------------------------
__global__ __launch_bounds__(256) void k_input_gemm(
    const float* __restrict__ x, const float* __restrict__ Wc,
    unsigned short* __restrict__ xwb)
{
    __shared__ float sWc[IN_F * OUT_F];
    for (int i = threadIdx.x; i < IN_F * OUT_F; i += 256) sWc[i] = Wc[i];
    __syncthreads();
    int wave = threadIdx.x >> 6;
    int lane = threadIdx.x & 63;
    int n = blockIdx.x * 4 + wave;           // N divisible by 4
    const float* xr = x + n * IN_F;
    float acc = 0.f;
    #pragma unroll
    for (int k = 0; k < IN_F; ++k) acc += xr[k] * sWc[k * OUT_F + lane];
    xwb[(size_t)n * OUT_F + lane] = f2bf(acc);
}

// ---------------------------------------------------------------------------
// K2: int histograms: cntD[node], cntB[edge]
// ---------------------------------------------------------------------------
__global__ __launch_bounds__(256) void k_hist(
    const int* __restrict__ ni, const int* __restrict__ ei,
    int* __restrict__ cntD, int* __restrict__ cntB)
{
    int p = blockIdx.x * 256 + threadIdx.x;  // grid exactly P/256
    atomicAdd(&cntD[ni[p]], 1);
    atomicAdd(&cntB[ei[p]], 1);
}

// ---------------------------------------------------------------------------
// K3: exclusive scan of both histograms + init per-bucket cursors
// ---------------------------------------------------------------------------
__global__ __launch_bounds__(SCAN_T) void k_scan(
    const int* __restrict__ cntB, const int* __restrict__ cntD,
    int* __restrict__ offE, int* __restrict__ offN,
    int* __restrict__ curE, int* __restrict__ curN)
{
    __shared__ int s[SCAN_T];
    const int* src = (blockIdx.x == 0) ? cntB : cntD;
    int* dst       = (blockIdx.x == 0) ? offE : offN;
    int* cur       = (blockIdx.x == 0) ? curE : curN;
    int t = threadIdx.x;
    int base = t * CHUNK;
    int sum = 0;
    for (int i = 0; i < CHUNK; ++i) {
        int idx = base + i;
        sum += (idx < N_NODES) ? src[idx] : 0;
    }
    s[t] = sum;
    __syncthreads();
    for (int off = 1; off < SCAN_T; off <<= 1) {
        int tmp = 0;
        if (t >= off) tmp = s[t - off];
        __syncthreads();
        if (t >= off) s[t] += tmp;
        __syncthreads();
    }
    int run = (t == 0) ? 0 : s[t - 1];
    for (int i = 0; i < CHUNK; ++i) {
        int idx = base + i;
        if (idx < N_NODES) {
            dst[idx] = run;
            if ((idx & 255) == 0) cur[idx >> BSHIFT] = run;
            run += src[idx];
        }
    }
}

// ---------------------------------------------------------------------------
// K4a: bucket phase 1 — bin pairs into per-bucket staging streams.
// stage entry: (key & 255) << 17 | value   (both ids < 2^17)
// ---------------------------------------------------------------------------
__global__ __launch_bounds__(256) void k_bucket1(
    const int* __restrict__ key, const int* __restrict__ val,
    int* __restrict__ cur, unsigned int* __restrict__ stage)
{
    __shared__ int hist[BUCKETS];
    __shared__ int base[BUCKETS];
    int t = threadIdx.x;
    for (int b = t; b < BUCKETS; b += 256) hist[b] = 0;
    __syncthreads();
    int p0 = blockIdx.x * CHUNK_P;
    for (int i = t; i < CHUNK_P; i += 256)
        atomicAdd(&hist[key[p0 + i] >> BSHIFT], 1);
    __syncthreads();
    for (int b = t; b < BUCKETS; b += 256) {
        int c = hist[b];
        base[b] = (c > 0) ? atomicAdd(&cur[b], c) : 0;
        hist[b] = 0;                      // reuse as local cursor
    }
    __syncthreads();
    for (int i = t; i < CHUNK_P; i += 256) {
        int k = key[p0 + i];
        int v = val[p0 + i];
        int bk = k >> BSHIFT;
        int pos = base[bk] + atomicAdd(&hist[bk], 1);
        stage[pos] = ((unsigned)(k & 255) << 17) | (unsigned)v;
    }
}

// ---------------------------------------------------------------------------
// K4b: bucket phase 2 — place staged entries into final CSR order.
// One block per bucket; LDS cursors seeded from off[] (which stay starts).
// ---------------------------------------------------------------------------
__global__ __launch_bounds__(256) void k_bucket2(
    const unsigned int* __restrict__ stage, const int* __restrict__ offK,
    int* __restrict__ adj)
{
    __shared__ int cur[256];
    int b = blockIdx.x;                   // BUCKETS blocks
    int t = threadIdx.x;
    int kbase = b << BSHIFT;
    int k = kbase + t;
    cur[t] = (k < N_NODES) ? offK[k] : 0;
    __syncthreads();
    int start = offK[kbase];
    int end = (b == BUCKETS - 1) ? P_PAIRS : offK[kbase + 256];
    for (int i = start + t; i < end; i += 256) {
        unsigned v = stage[i];
        int kl = v >> 17;
        int pos = atomicAdd(&cur[kl], 1);
        adj[pos] = (int)(v & 0x1FFFF);
    }
}

// ---------------------------------------------------------------------------
// K5: per-edge gather-reduce: ef[e] = B_inv * sum xw[n in edge]   (bf16 I/O)
// ---------------------------------------------------------------------------
__global__ __launch_bounds__(256) void k_edge(
    const int* __restrict__ adjE, const int* __restrict__ offE,
    const int* __restrict__ cntB, const unsigned short* __restrict__ xwb,
    unsigned short* __restrict__ efb)
{
    int wave = threadIdx.x >> 6;
    int lane = threadIdx.x & 63;
    int sub = lane >> 3;
    int cg  = lane & 7;
    int e = blockIdx.x * 4 + wave;           // grid exactly N/4
    int len = cntB[e];
    int start = offE[e];
    int end = start + len;

    float acc[8];
    #pragma unroll
    for (int j = 0; j < 8; ++j) acc[j] = 0.f;

    int i = start + sub;
    for (; i + 8 < end; i += 16) {           // 2 rows in flight per lane
        int n0 = adjE[i];
        int n1 = adjE[i + 8];
        u16x8 v0 = *(const u16x8*)(xwb + (size_t)n0 * OUT_F + cg * 8);
        u16x8 v1 = *(const u16x8*)(xwb + (size_t)n1 * OUT_F + cg * 8);
        #pragma unroll
        for (int j = 0; j < 8; ++j) acc[j] += bf2f(v0[j]);
        #pragma unroll
        for (int j = 0; j < 8; ++j) acc[j] += bf2f(v1[j]);
    }
    if (i < end) {
        int n0 = adjE[i];
        u16x8 v0 = *(const u16x8*)(xwb + (size_t)n0 * OUT_F + cg * 8);
        #pragma unroll
        for (int j = 0; j < 8; ++j) acc[j] += bf2f(v0[j]);
    }

    #pragma unroll
    for (int off = 8; off < 64; off <<= 1) {
        #pragma unroll
        for (int j = 0; j < 8; ++j) acc[j] += __shfl_xor(acc[j], off, 64);
    }

    float binv = (len > 0) ? 1.f / (float)len : 0.f;
    if (sub == 0) {
        u16x8 o;
        #pragma unroll
        for (int j = 0; j < 8; ++j) o[j] = f2bf(acc[j] * binv);
        *(u16x8*)(efb + (size_t)e * OUT_F + cg * 8) = o;
    }
}

// ---------------------------------------------------------------------------
// K6: per-node gather-reduce (bf16 ef) + conv bias + 64x64 MLP GEMM (shfl)
//     + BN partials. grid-stride waves; h (f32) -> d_out.
// ---------------------------------------------------------------------------
__global__ __launch_bounds__(256) void k_node_mlp(
    const int* __restrict__ adjN, const int* __restrict__ offN,
    const int* __restrict__ cntD, const unsigned short* __restrict__ efb,
    const float* __restrict__ bconv, const float* __restrict__ Wm,
    const float* __restrict__ bm, float* __restrict__ h,
    float* __restrict__ bns)
{
    __shared__ float sW[OUT_F * OUT_F];
    for (int t = threadIdx.x; t < OUT_F * OUT_F; t += 256) sW[t] = Wm[t];
    __syncthreads();
    int lane = threadIdx.x & 63;
    int sub = lane >> 3;
    int cg  = lane & 7;
    float bcv[8];
    #pragma unroll
    for (int j = 0; j < 8; ++j) bcv[j] = bconv[cg * 8 + j];
    float bmc = bm[lane];

    int gw = (blockIdx.x * 256 + threadIdx.x) >> 6;
    int nw = gridDim.x * 4;
    float s = 0.f, s2 = 0.f;

    for (int n = gw; n < N_NODES; n += nw) {
        int len = cntD[n];
        int start = offN[n];
        int end = start + len;

        float acc[8];
        #pragma unroll
        for (int j = 0; j < 8; ++j) acc[j] = 0.f;

        int i = start + sub;
        for (; i + 8 < end; i += 16) {
            int e0 = adjN[i];
            int e1 = adjN[i + 8];
            u16x8 v0 = *(const u16x8*)(efb + (size_t)e0 * OUT_F + cg * 8);
            u16x8 v1 = *(const u16x8*)(efb + (size_t)e1 * OUT_F + cg * 8);
            #pragma unroll
            for (int j = 0; j < 8; ++j) acc[j] += bf2f(v0[j]);
            #pragma unroll
            for (int j = 0; j < 8; ++j) acc[j] += bf2f(v1[j]);
        }
        if (i < end) {
            int e0 = adjN[i];
            u16x8 v0 = *(const u16x8*)(efb + (size_t)e0 * OUT_F + cg * 8);
            #pragma unroll
            for (int j = 0; j < 8; ++j) acc[j] += bf2f(v0[j]);
        }

        #pragma unroll
        for (int off = 8; off < 64; off <<= 1) {
            #pragma unroll
            for (int j = 0; j < 8; ++j) acc[j] += __shfl_xor(acc[j], off, 64);
        }

        float dinv = (len > 0) ? 1.f / (float)len : 0.f;
        float cvv[8];
        #pragma unroll
        for (int j = 0; j < 8; ++j) cvv[j] = acc[j] * dinv + bcv[j];

        float a = bmc;
        #pragma unroll
        for (int c = 0; c < OUT_F; ++c)
            a += __shfl(cvv[c & 7], c >> 3, 64) * sW[c * OUT_F + lane];

        h[(size_t)n * OUT_F + lane] = a;
        s  += a;
        s2 += a * a;
    }
    atomicAdd(&bns[lane], s);
    atomicAdd(&bns[64 + lane], s2);
}

// ---------------------------------------------------------------------------
// K7: BN normalize + LeakyReLU + residual (x @ W_res + b_res) + LeakyReLU
// ---------------------------------------------------------------------------
__global__ __launch_bounds__(256) void k_final(
    const float* __restrict__ x, const float* __restrict__ Wr,
    const float* __restrict__ br, const float* __restrict__ bns,
    const float* __restrict__ gamma, const float* __restrict__ beta,
    float* __restrict__ out)
{
    __shared__ float sWr[IN_F * OUT_F];
    for (int i = threadIdx.x; i < IN_F * OUT_F; i += 256) sWr[i] = Wr[i];
    __syncthreads();
    int wave = threadIdx.x >> 6;
    int lane = threadIdx.x & 63;
    int n = blockIdx.x * 4 + wave;
    const float inv_n = 1.f / (float)N_NODES;
    float mean = bns[lane] * inv_n;
    float var  = bns[64 + lane] * inv_n - mean * mean;
    float rstd = rsqrtf(var + BN_EPS);
    float g = gamma[lane], bt = beta[lane];

    const float* xr = x + n * IN_F;
    float r = br[lane];
    #pragma unroll
    for (int k = 0; k < IN_F; ++k) r += xr[k] * sWr[k * OUT_F + lane];

    float hv = out[(size_t)n * OUT_F + lane];
    float a = g * (hv - mean) * rstd + bt;
    a = (a >= 0.f) ? a : SLOPE * a;
    float y = a + r;
    out[(size_t)n * OUT_F + lane] = (y >= 0.f) ? y : SLOPE * y;
}

// ---------------------------------------------------------------------------
extern "C" void kernel_launch(void* const* d_in, const int* in_sizes, int n_in,
                              void* d_out, int out_size, void* d_ws, size_t ws_size,
                              hipStream_t stream) {
    const float* x     = (const float*)d_in[0];
    const int*   hidx  = (const int*)d_in[1];
    const int*   ni    = hidx;               // row 0: node idx
    const int*   ei    = hidx + P_PAIRS;     // row 1: edge idx
    const float* Wc    = (const float*)d_in[2];
    const float* bc    = (const float*)d_in[3];
    const float* Wm    = (const float*)d_in[4];
    const float* bm    = (const float*)d_in[5];
    const float* gamma = (const float*)d_in[6];
    const float* beta  = (const float*)d_in[7];
    const float* Wr    = (const float*)d_in[8];
    const float* br    = (const float*)d_in[9];
    float* out = (float*)d_out;

    // ws: [cntB N][cntD N][bns 128f][offE N][offN N][curE 391][curN 391]
    //     [adjE P][adjN P][stage/efb P u32]  ~= 42 MB
    int*   cntB = (int*)d_ws;
    int*   cntD = cntB + N_NODES;
    float* bns  = (float*)(cntD + N_NODES);
    int*   offE = (int*)(bns + 128);
    int*   offN = offE + N_NODES;
    int*   curE = offN + N_NODES;
    int*   curN = curE + BUCKETS;
    int*   adjE = curN + BUCKETS;
    int*   adjN = adjE + P_PAIRS;
    unsigned int* stage = (unsigned int*)(adjN + P_PAIRS);
    unsigned short* efb = (unsigned short*)stage;   // aliased: stage dead before k_edge

    unsigned short* xwb = (unsigned short*)d_out;   // xw staged in d_out

    hipMemsetAsync(cntB, 0, (size_t)(2 * N_NODES) * sizeof(int) + 128 * sizeof(float), stream);

    k_input_gemm<<<N_NODES / 4, 256, 0, stream>>>(x, Wc, xwb);
    k_hist<<<P_PAIRS / 256, 256, 0, stream>>>(ni, ei, cntD, cntB);
    k_scan<<<2, SCAN_T, 0, stream>>>(cntB, cntD, offE, offN, curE, curN);

    // edge-side CSR via bucketed two-phase build (stage aliased with efb)
    k_bucket1<<<P_PAIRS / CHUNK_P, 256, 0, stream>>>(ei, ni, curE, stage);
    k_bucket2<<<BUCKETS, 256, 0, stream>>>(stage, offE, adjE);
    // node-side CSR
    k_bucket1<<<P_PAIRS / CHUNK_P, 256, 0, stream>>>(ni, ei, curN, stage);
    k_bucket2<<<BUCKETS, 256, 0, stream>>>(stage, offN, adjN);

    k_edge<<<N_NODES / 4, 256, 0, stream>>>(adjE, offE, cntB, xwb, efb);
    k_node_mlp<<<2048, 256, 0, stream>>>(adjN, offN, cntD, efb, bc, Wm, bm, out, bns);
    k_final<<<N_NODES / 4, 256, 0, stream>>>(x, Wr, br, bns, gamma, beta, out);
}

// Round 5
// 868.375 us; speedup vs baseline: 2.3120x; 1.1861x over previous
//
#include <hip/hip_runtime.h>

#define N_NODES 100000
#define P_PAIRS 3200000
#define IN_F    19
#define OUT_F   64
#define BN_EPS  1e-5f
#define SLOPE   0.01f
#define BSHIFT  8       // 256 keys per bucket
#define BUCKETS 391     // ceil(N_NODES / 256)
#define CAP     9000    // staging capacity per bucket (mean 8184, sd ~90)
#define CHUNK_P 6400    // pairs per bucket1 block (P / 6400 = 500 blocks)
#define NCH     4       // channel chunks
#define CH_F    16      // channels per chunk (16*2B = 32 B rows, L2-resident 3.2MB table)

typedef __attribute__((ext_vector_type(8))) unsigned short u16x8;

__device__ __forceinline__ float bf2f(unsigned short h) {
    return __uint_as_float(((unsigned)h) << 16);
}
__device__ __forceinline__ unsigned short f2bf(float f) {
    unsigned u = __float_as_uint(f);
    return (unsigned short)((u + 0x7FFF + ((u >> 16) & 1)) >> 16);  // RNE
}

// ---------------------------------------------------------------------------
// K1: xw = x @ W_conv  -> bf16 chunk-major table [4][N][16] (in d_out lower half)
// ---------------------------------------------------------------------------
__global__ __launch_bounds__(256) void k_input_gemm(
    const float* __restrict__ x, const float* __restrict__ Wc,
    unsigned short* __restrict__ xwb)
{
    __shared__ float sWc[IN_F * OUT_F];
    for (int i = threadIdx.x; i < IN_F * OUT_F; i += 256) sWc[i] = Wc[i];
    __syncthreads();
    int wave = threadIdx.x >> 6;
    int lane = threadIdx.x & 63;
    int n = blockIdx.x * 4 + wave;           // N divisible by 4
    const float* xr = x + n * IN_F;
    float acc = 0.f;
    #pragma unroll
    for (int k = 0; k < IN_F; ++k) acc += xr[k] * sWc[k * OUT_F + lane];
    // chunk-major store
    xwb[(size_t)(lane >> 4) * (N_NODES * CH_F) + (size_t)n * CH_F + (lane & 15)] = f2bf(acc);
}

// ---------------------------------------------------------------------------
// K2: bucket phase 1 — bin pairs into fixed-capacity per-bucket staging.
// stage entry: (key & 255) << 17 | value  (both ids < 2^17)
// ---------------------------------------------------------------------------
__global__ __launch_bounds__(256) void k_bucket1(
    const int* __restrict__ key, const int* __restrict__ val,
    int* __restrict__ cur, unsigned int* __restrict__ stage)
{
    __shared__ int hist[BUCKETS];
    __shared__ int base_s[BUCKETS];
    int t = threadIdx.x;
    for (int b = t; b < BUCKETS; b += 256) hist[b] = 0;
    __syncthreads();
    int p0 = blockIdx.x * CHUNK_P;
    for (int i = t; i < CHUNK_P; i += 256)
        atomicAdd(&hist[key[p0 + i] >> BSHIFT], 1);
    __syncthreads();
    for (int b = t; b < BUCKETS; b += 256) {
        int c = hist[b];
        base_s[b] = (c > 0) ? atomicAdd(&cur[b], c) : 0;
        hist[b] = 0;                      // reuse as local cursor
    }
    __syncthreads();
    for (int i = t; i < CHUNK_P; i += 256) {
        int k = key[p0 + i];
        int v = val[p0 + i];
        int bk = k >> BSHIFT;
        int pos = base_s[bk] + atomicAdd(&hist[bk], 1);
        if (pos < CAP)                    // 9-sigma guard; never expected
            stage[(size_t)bk * CAP + pos] = ((unsigned)(k & 255) << 17) | (unsigned)v;
    }
}

// ---------------------------------------------------------------------------
// K3: mini-scan of 391 bucket totals -> bucket base offsets
// ---------------------------------------------------------------------------
__global__ __launch_bounds__(512) void k_minscan(
    const int* __restrict__ cur, int* __restrict__ base)
{
    __shared__ int s[512];
    int t = threadIdx.x;
    int v = (t < BUCKETS) ? cur[t] : 0;
    s[t] = v;
    __syncthreads();
    for (int off = 1; off < 512; off <<= 1) {
        int tmp = (t >= off) ? s[t - off] : 0;
        __syncthreads();
        s[t] += tmp;
        __syncthreads();
    }
    if (t < BUCKETS) base[t] = s[t] - v;   // exclusive
}

// ---------------------------------------------------------------------------
// K4: bucket phase 2 — per-key count + in-block scan -> off/len, then place.
// One block per bucket.
// ---------------------------------------------------------------------------
__global__ __launch_bounds__(256) void k_bucket2(
    const unsigned int* __restrict__ stage, const int* __restrict__ cur,
    const int* __restrict__ base, int* __restrict__ adj,
    int* __restrict__ offK, int* __restrict__ lenK)
{
    __shared__ int cnt[256];
    __shared__ int s[256];
    __shared__ int cur_l[256];
    int b = blockIdx.x;
    int t = threadIdx.x;
    int m = cur[b]; if (m > CAP) m = CAP;
    size_t sbase = (size_t)b * CAP;
    cnt[t] = 0;
    __syncthreads();
    for (int i = t; i < m; i += 256)
        atomicAdd(&cnt[stage[sbase + i] >> 17], 1);
    __syncthreads();
    int c = cnt[t];
    s[t] = c;
    __syncthreads();
    for (int off = 1; off < 256; off <<= 1) {
        int tmp = (t >= off) ? s[t - off] : 0;
        __syncthreads();
        s[t] += tmp;
        __syncthreads();
    }
    int keyoff = base[b] + s[t] - c;       // global exclusive offset for key
    int k = (b << BSHIFT) + t;
    if (k < N_NODES) { offK[k] = keyoff; lenK[k] = c; }
    cur_l[t] = keyoff;
    __syncthreads();
    for (int i = t; i < m; i += 256) {
        unsigned v = stage[sbase + i];
        int kl = v >> 17;
        int pos = atomicAdd(&cur_l[kl], 1);
        adj[pos] = (int)(v & 0x1FFFF);
    }
}

// ---------------------------------------------------------------------------
// K5: hop1, one channel chunk: ef_c[e] = B_inv * sum xw_c[n in edge]
// wave per edge; lane = (sub 0..31 row slot, cg 0..1 8-chan half of chunk)
// ---------------------------------------------------------------------------
__global__ __launch_bounds__(256) void k_hop1(
    const int* __restrict__ adjE, const int* __restrict__ offE,
    const int* __restrict__ lenE, const unsigned short* __restrict__ xwc,
    unsigned short* __restrict__ efc)
{
    int lane = threadIdx.x & 63;
    int sub = lane >> 1;
    int cg  = lane & 1;
    int e = blockIdx.x * 4 + (threadIdx.x >> 6);
    int len = lenE[e];
    int start = offE[e];
    int end = start + len;

    float acc[8];
    #pragma unroll
    for (int j = 0; j < 8; ++j) acc[j] = 0.f;

    for (int i = start + sub; i < end; i += 32) {
        int idx = __builtin_nontemporal_load(&adjE[i]);
        u16x8 v = *(const u16x8*)(xwc + (size_t)idx * CH_F + cg * 8);
        #pragma unroll
        for (int j = 0; j < 8; ++j) acc[j] += bf2f(v[j]);
    }
    #pragma unroll
    for (int m = 2; m < 64; m <<= 1) {     // reduce over sub (lane bits 1..5)
        #pragma unroll
        for (int j = 0; j < 8; ++j) acc[j] += __shfl_xor(acc[j], m, 64);
    }
    if (lane < 2) {
        float binv = (len > 0) ? 1.f / (float)len : 0.f;
        u16x8 o;
        #pragma unroll
        for (int j = 0; j < 8; ++j) o[j] = f2bf(acc[j] * binv);
        __builtin_nontemporal_store(o, (u16x8*)(efc + (size_t)e * CH_F + cg * 8));
    }
}

// ---------------------------------------------------------------------------
// K6: hop2, one channel chunk: cv_c[n] = D_inv * sum ef_c[e in node] + bconv_c
// ---------------------------------------------------------------------------
__global__ __launch_bounds__(256) void k_hop2(
    const int* __restrict__ adjN, const int* __restrict__ offN,
    const int* __restrict__ lenN, const unsigned short* __restrict__ efc,
    unsigned short* __restrict__ cvc, const float* __restrict__ bcc)
{
    int lane = threadIdx.x & 63;
    int sub = lane >> 1;
    int cg  = lane & 1;
    int n = blockIdx.x * 4 + (threadIdx.x >> 6);
    int len = lenN[n];
    int start = offN[n];
    int end = start + len;

    float acc[8];
    #pragma unroll
    for (int j = 0; j < 8; ++j) acc[j] = 0.f;

    for (int i = start + sub; i < end; i += 32) {
        int idx = __builtin_nontemporal_load(&adjN[i]);
        u16x8 v = *(const u16x8*)(efc + (size_t)idx * CH_F + cg * 8);
        #pragma unroll
        for (int j = 0; j < 8; ++j) acc[j] += bf2f(v[j]);
    }
    #pragma unroll
    for (int m = 2; m < 64; m <<= 1) {
        #pragma unroll
        for (int j = 0; j < 8; ++j) acc[j] += __shfl_xor(acc[j], m, 64);
    }
    if (lane < 2) {
        float dinv = (len > 0) ? 1.f / (float)len : 0.f;
        u16x8 o;
        #pragma unroll
        for (int j = 0; j < 8; ++j) o[j] = f2bf(acc[j] * dinv + bcc[cg * 8 + j]);
        __builtin_nontemporal_store(o, (u16x8*)(cvc + (size_t)n * CH_F + cg * 8));
    }
}

// ---------------------------------------------------------------------------
// K7: MLP 64x64 GEMM over bf16 cv (chunk-major) + BN partials. Wm hoisted
// into 64 VGPRs per lane; h (f32) -> d_out.
// ---------------------------------------------------------------------------
__global__ __launch_bounds__(256) void k_mlp(
    const unsigned short* __restrict__ cvb, const float* __restrict__ Wm,
    const float* __restrict__ bm, float* __restrict__ h,
    float* __restrict__ bns)
{
    int lane = threadIdx.x & 63;
    float w[OUT_F];
    #pragma unroll
    for (int k = 0; k < OUT_F; ++k) w[k] = Wm[k * OUT_F + lane];
    float bmc = bm[lane];
    size_t coff = (size_t)(lane >> 4) * (N_NODES * CH_F) + (lane & 15);

    int gw = (blockIdx.x * 256 + threadIdx.x) >> 6;
    int nw = gridDim.x * 4;
    float s = 0.f, s2 = 0.f;
    for (int n = gw; n < N_NODES; n += nw) {
        float cv = bf2f(cvb[coff + (size_t)n * CH_F]);
        float a = bmc;
        #pragma unroll
        for (int k = 0; k < OUT_F; ++k)
            a += __shfl(cv, ((k >> 4) << 4) | (k & 15), 64) * w[k];
        h[(size_t)n * OUT_F + lane] = a;
        s  += a;
        s2 += a * a;
    }
    atomicAdd(&bns[lane], s);
    atomicAdd(&bns[64 + lane], s2);
}

// ---------------------------------------------------------------------------
// K8: BN normalize + LeakyReLU + residual (x @ W_res + b_res) + LeakyReLU
// ---------------------------------------------------------------------------
__global__ __launch_bounds__(256) void k_final(
    const float* __restrict__ x, const float* __restrict__ Wr,
    const float* __restrict__ br, const float* __restrict__ bns,
    const float* __restrict__ gamma, const float* __restrict__ beta,
    float* __restrict__ out)
{
    __shared__ float sWr[IN_F * OUT_F];
    for (int i = threadIdx.x; i < IN_F * OUT_F; i += 256) sWr[i] = Wr[i];
    __syncthreads();
    int wave = threadIdx.x >> 6;
    int lane = threadIdx.x & 63;
    int n = blockIdx.x * 4 + wave;
    const float inv_n = 1.f / (float)N_NODES;
    float mean = bns[lane] * inv_n;
    float var  = bns[64 + lane] * inv_n - mean * mean;
    float rstd = rsqrtf(var + BN_EPS);
    float g = gamma[lane], bt = beta[lane];

    const float* xr = x + n * IN_F;
    float r = br[lane];
    #pragma unroll
    for (int k = 0; k < IN_F; ++k) r += xr[k] * sWr[k * OUT_F + lane];

    float hv = out[(size_t)n * OUT_F + lane];
    float a = g * (hv - mean) * rstd + bt;
    a = (a >= 0.f) ? a : SLOPE * a;
    float y = a + r;
    out[(size_t)n * OUT_F + lane] = (y >= 0.f) ? y : SLOPE * y;
}

// ---------------------------------------------------------------------------
extern "C" void kernel_launch(void* const* d_in, const int* in_sizes, int n_in,
                              void* d_out, int out_size, void* d_ws, size_t ws_size,
                              hipStream_t stream) {
    const float* x     = (const float*)d_in[0];
    const int*   hidx  = (const int*)d_in[1];
    const int*   ni    = hidx;               // row 0: node idx
    const int*   ei    = hidx + P_PAIRS;     // row 1: edge idx
    const float* Wc    = (const float*)d_in[2];
    const float* bc    = (const float*)d_in[3];
    const float* Wm    = (const float*)d_in[4];
    const float* bm    = (const float*)d_in[5];
    const float* gamma = (const float*)d_in[6];
    const float* beta  = (const float*)d_in[7];
    const float* Wr    = (const float*)d_in[8];
    const float* br    = (const float*)d_in[9];
    float* out = (float*)d_out;

    // --- ws (~40 MB): [adjE P][adjN P][stage 391*9000 u32 / efb alias][bns 128f]
    int* adjE = (int*)d_ws;
    int* adjN = adjE + P_PAIRS;
    unsigned int* stage = (unsigned int*)(adjN + P_PAIRS);
    unsigned short* efb = (unsigned short*)stage;        // [4][N][16], alias ok (stage dead)
    float* bns = (float*)(stage + (size_t)BUCKETS * CAP);
    unsigned short* cvb = (unsigned short*)adjE;         // [4][N][16], adjE dead after hop1

    // --- d_out lower half: xwb [4][N][16] bf16 (dead before h); upper half: small arrays
    unsigned short* xwb = (unsigned short*)d_out;
    int* smalls = (int*)(out + (size_t)N_NODES * OUT_F / 2);  // float idx 3.2M = 12.8MB
    int* curE  = smalls;
    int* curN  = curE + BUCKETS;
    int* baseE = curN + BUCKETS;
    int* baseN = baseE + BUCKETS;
    int* offE  = baseN + BUCKETS;
    int* lenE  = offE + N_NODES;
    int* offN  = lenE + N_NODES;
    int* lenN  = offN + N_NODES;

    hipMemsetAsync(bns, 0, 128 * sizeof(float), stream);
    hipMemsetAsync(curE, 0, 2 * BUCKETS * sizeof(int), stream);

    k_input_gemm<<<N_NODES / 4, 256, 0, stream>>>(x, Wc, xwb);

    // edge-side CSR
    k_bucket1<<<P_PAIRS / CHUNK_P, 256, 0, stream>>>(ei, ni, curE, stage);
    k_minscan<<<1, 512, 0, stream>>>(curE, baseE);
    k_bucket2<<<BUCKETS, 256, 0, stream>>>(stage, curE, baseE, adjE, offE, lenE);
    // node-side CSR (stage reused)
    k_bucket1<<<P_PAIRS / CHUNK_P, 256, 0, stream>>>(ni, ei, curN, stage);
    k_minscan<<<1, 512, 0, stream>>>(curN, baseN);
    k_bucket2<<<BUCKETS, 256, 0, stream>>>(stage, curN, baseN, adjN, offN, lenN);

    // hop1: per-chunk L2-resident gathers (stage dead -> efb)
    for (int c = 0; c < NCH; ++c)
        k_hop1<<<N_NODES / 4, 256, 0, stream>>>(
            adjE, offE, lenE,
            xwb + (size_t)c * N_NODES * CH_F,
            efb + (size_t)c * N_NODES * CH_F);

    // hop2: per-chunk (adjE dead -> cvb)
    for (int c = 0; c < NCH; ++c)
        k_hop2<<<N_NODES / 4, 256, 0, stream>>>(
            adjN, offN, lenN,
            efb + (size_t)c * N_NODES * CH_F,
            cvb + (size_t)c * N_NODES * CH_F,
            bc + c * CH_F);

    k_mlp<<<1024, 256, 0, stream>>>(cvb, Wm, bm, out, bns);
    k_final<<<N_NODES / 4, 256, 0, stream>>>(x, Wr, br, bns, gamma, beta, out);
}

// Round 6
// 813.353 us; speedup vs baseline: 2.4684x; 1.0676x over previous
//
#include <hip/hip_runtime.h>

#define N_NODES 100000
#define P_PAIRS 3200000
#define IN_F    19
#define OUT_F   64
#define BN_EPS  1e-5f
#define SLOPE   0.01f
#define BSHIFT  8       // 256 keys per bucket
#define BUCKETS 391     // ceil(N_NODES / 256)
#define CAP     9000    // staging capacity per bucket (mean 8184, sd ~90)
#define CHUNK_P 6400    // pairs per bucket1 block (P / 6400 = 500 blocks)
#define NCH     4       // channel chunks
#define CH_F    16      // channels per chunk (32 B rows, 3.2 MB table -> L2-resident)

typedef __attribute__((ext_vector_type(8))) unsigned short u16x8;
typedef __attribute__((ext_vector_type(8))) short bf16x8;
typedef __attribute__((ext_vector_type(4))) float f32x4;

__device__ __forceinline__ float bf2f(unsigned short h) {
    return __uint_as_float(((unsigned)h) << 16);
}
__device__ __forceinline__ unsigned short f2bf(float f) {
    unsigned u = __float_as_uint(f);
    return (unsigned short)((u + 0x7FFF + ((u >> 16) & 1)) >> 16);  // RNE
}

// ---------------------------------------------------------------------------
// K1: xw = x @ W_conv  -> bf16 chunk-major table [4][N][16] (in d_out lower half)
// ---------------------------------------------------------------------------
__global__ __launch_bounds__(256) void k_input_gemm(
    const float* __restrict__ x, const float* __restrict__ Wc,
    unsigned short* __restrict__ xwb)
{
    __shared__ float sWc[IN_F * OUT_F];
    for (int i = threadIdx.x; i < IN_F * OUT_F; i += 256) sWc[i] = Wc[i];
    __syncthreads();
    int wave = threadIdx.x >> 6;
    int lane = threadIdx.x & 63;
    int n = blockIdx.x * 4 + wave;           // N divisible by 4
    const float* xr = x + n * IN_F;
    float acc = 0.f;
    #pragma unroll
    for (int k = 0; k < IN_F; ++k) acc += xr[k] * sWc[k * OUT_F + lane];
    xwb[(size_t)(lane >> 4) * (N_NODES * CH_F) + (size_t)n * CH_F + (lane & 15)] = f2bf(acc);
}

// ---------------------------------------------------------------------------
// K2: bucket phase 1 — bin pairs into fixed-capacity per-bucket staging.
// stage entry: (key & 255) << 17 | value  (both ids < 2^17)
// ---------------------------------------------------------------------------
__global__ __launch_bounds__(256) void k_bucket1(
    const int* __restrict__ key, const int* __restrict__ val,
    int* __restrict__ cur, unsigned int* __restrict__ stage)
{
    __shared__ int hist[BUCKETS];
    __shared__ int base_s[BUCKETS];
    int t = threadIdx.x;
    for (int b = t; b < BUCKETS; b += 256) hist[b] = 0;
    __syncthreads();
    int p0 = blockIdx.x * CHUNK_P;
    for (int i = t; i < CHUNK_P; i += 256)
        atomicAdd(&hist[key[p0 + i] >> BSHIFT], 1);
    __syncthreads();
    for (int b = t; b < BUCKETS; b += 256) {
        int c = hist[b];
        base_s[b] = (c > 0) ? atomicAdd(&cur[b], c) : 0;
        hist[b] = 0;                      // reuse as local cursor
    }
    __syncthreads();
    for (int i = t; i < CHUNK_P; i += 256) {
        int k = key[p0 + i];
        int v = val[p0 + i];
        int bk = k >> BSHIFT;
        int pos = base_s[bk] + atomicAdd(&hist[bk], 1);
        if (pos < CAP)                    // 9-sigma guard; never expected
            stage[(size_t)bk * CAP + pos] = ((unsigned)(k & 255) << 17) | (unsigned)v;
    }
}

// ---------------------------------------------------------------------------
// K3: mini-scan of 391 bucket totals -> bucket base offsets
// ---------------------------------------------------------------------------
__global__ __launch_bounds__(512) void k_minscan(
    const int* __restrict__ cur, int* __restrict__ base)
{
    __shared__ int s[512];
    int t = threadIdx.x;
    int v = (t < BUCKETS) ? cur[t] : 0;
    s[t] = v;
    __syncthreads();
    for (int off = 1; off < 512; off <<= 1) {
        int tmp = (t >= off) ? s[t - off] : 0;
        __syncthreads();
        s[t] += tmp;
        __syncthreads();
    }
    if (t < BUCKETS) base[t] = s[t] - v;   // exclusive
}

// ---------------------------------------------------------------------------
// K4: bucket phase 2 — per-key count + in-block scan -> off/len, then place.
// ---------------------------------------------------------------------------
__global__ __launch_bounds__(256) void k_bucket2(
    const unsigned int* __restrict__ stage, const int* __restrict__ cur,
    const int* __restrict__ base, int* __restrict__ adj,
    int* __restrict__ offK, int* __restrict__ lenK)
{
    __shared__ int cnt[256];
    __shared__ int s[256];
    __shared__ int cur_l[256];
    int b = blockIdx.x;
    int t = threadIdx.x;
    int m = cur[b]; if (m > CAP) m = CAP;
    size_t sbase = (size_t)b * CAP;
    cnt[t] = 0;
    __syncthreads();
    for (int i = t; i < m; i += 256)
        atomicAdd(&cnt[stage[sbase + i] >> 17], 1);
    __syncthreads();
    int c = cnt[t];
    s[t] = c;
    __syncthreads();
    for (int off = 1; off < 256; off <<= 1) {
        int tmp = (t >= off) ? s[t - off] : 0;
        __syncthreads();
        s[t] += tmp;
        __syncthreads();
    }
    int keyoff = base[b] + s[t] - c;       // global exclusive offset for key
    int k = (b << BSHIFT) + t;
    if (k < N_NODES) { offK[k] = keyoff; lenK[k] = c; }
    cur_l[t] = keyoff;
    __syncthreads();
    for (int i = t; i < m; i += 256) {
        unsigned v = stage[sbase + i];
        int kl = v >> 17;
        int pos = atomicAdd(&cur_l[kl], 1);
        adj[pos] = (int)(v & 0x1FFFF);
    }
}

// ---------------------------------------------------------------------------
// K5: hop1, one channel chunk: ef_c[e] = B_inv * sum xw_c[n in edge]
// ---------------------------------------------------------------------------
__global__ __launch_bounds__(256) void k_hop1(
    const int* __restrict__ adjE, const int* __restrict__ offE,
    const int* __restrict__ lenE, const unsigned short* __restrict__ xwc,
    unsigned short* __restrict__ efc)
{
    int lane = threadIdx.x & 63;
    int sub = lane >> 1;
    int cg  = lane & 1;
    int e = blockIdx.x * 4 + (threadIdx.x >> 6);
    int len = lenE[e];
    int start = offE[e];
    int end = start + len;

    float acc[8];
    #pragma unroll
    for (int j = 0; j < 8; ++j) acc[j] = 0.f;

    for (int i = start + sub; i < end; i += 32) {
        int idx = __builtin_nontemporal_load(&adjE[i]);
        u16x8 v = *(const u16x8*)(xwc + (size_t)idx * CH_F + cg * 8);
        #pragma unroll
        for (int j = 0; j < 8; ++j) acc[j] += bf2f(v[j]);
    }
    #pragma unroll
    for (int m = 2; m < 64; m <<= 1) {
        #pragma unroll
        for (int j = 0; j < 8; ++j) acc[j] += __shfl_xor(acc[j], m, 64);
    }
    if (lane < 2) {
        float binv = (len > 0) ? 1.f / (float)len : 0.f;
        u16x8 o;
        #pragma unroll
        for (int j = 0; j < 8; ++j) o[j] = f2bf(acc[j] * binv);
        __builtin_nontemporal_store(o, (u16x8*)(efc + (size_t)e * CH_F + cg * 8));
    }
}

// ---------------------------------------------------------------------------
// K6: hop2, one channel chunk: cv_c[n] = D_inv * sum ef_c[e in node] + bconv_c
// ---------------------------------------------------------------------------
__global__ __launch_bounds__(256) void k_hop2(
    const int* __restrict__ adjN, const int* __restrict__ offN,
    const int* __restrict__ lenN, const unsigned short* __restrict__ efc,
    unsigned short* __restrict__ cvc, const float* __restrict__ bcc)
{
    int lane = threadIdx.x & 63;
    int sub = lane >> 1;
    int cg  = lane & 1;
    int n = blockIdx.x * 4 + (threadIdx.x >> 6);
    int len = lenN[n];
    int start = offN[n];
    int end = start + len;

    float acc[8];
    #pragma unroll
    for (int j = 0; j < 8; ++j) acc[j] = 0.f;

    for (int i = start + sub; i < end; i += 32) {
        int idx = __builtin_nontemporal_load(&adjN[i]);
        u16x8 v = *(const u16x8*)(efc + (size_t)idx * CH_F + cg * 8);
        #pragma unroll
        for (int j = 0; j < 8; ++j) acc[j] += bf2f(v[j]);
    }
    #pragma unroll
    for (int m = 2; m < 64; m <<= 1) {
        #pragma unroll
        for (int j = 0; j < 8; ++j) acc[j] += __shfl_xor(acc[j], m, 64);
    }
    if (lane < 2) {
        float dinv = (len > 0) ? 1.f / (float)len : 0.f;
        u16x8 o;
        #pragma unroll
        for (int j = 0; j < 8; ++j) o[j] = f2bf(acc[j] * dinv + bcc[cg * 8 + j]);
        __builtin_nontemporal_store(o, (u16x8*)(cvc + (size_t)n * CH_F + cg * 8));
    }
}

// ---------------------------------------------------------------------------
// K7: MLP via MFMA: h = cv @ Wm + bm  (+ BN partial sums)
// one wave per 16-node row-tile; A = cv (bf16, chunk-major), B = Wm in regs.
// mfma_f32_16x16x32_bf16: A[m=lane&15][k=quad*8+j]; D: col=lane&15,
// row=quad*4+reg. Chunk-major cv maps A's k-seg to one contiguous u16x8.
// ---------------------------------------------------------------------------
__global__ __launch_bounds__(256) void k_mlp_mfma(
    const unsigned short* __restrict__ cvb, const float* __restrict__ Wm,
    const float* __restrict__ bm, float* __restrict__ h,
    float* __restrict__ bns)
{
    int lane = threadIdx.x & 63;
    int q = lane >> 4;                     // quad: k-segment / D row group
    int c = lane & 15;                     // A row / D col (within tile)

    // B fragments: 4 col-tiles x 2 k-halves; B[k=kh*32+q*8+j][col=t*16+c]
    bf16x8 bf[4][2];
    #pragma unroll
    for (int t = 0; t < 4; ++t)
        #pragma unroll
        for (int kh = 0; kh < 2; ++kh)
            #pragma unroll
            for (int j = 0; j < 8; ++j)
                bf[t][kh][j] = (short)f2bf(Wm[(kh * 32 + q * 8 + j) * OUT_F + t * 16 + c]);
    float bmv[4];
    #pragma unroll
    for (int t = 0; t < 4; ++t) bmv[t] = bm[t * 16 + c];

    float s[4], s2[4];
    #pragma unroll
    for (int t = 0; t < 4; ++t) { s[t] = 0.f; s2[t] = 0.f; }

    int gw = (blockIdx.x * 256 + threadIdx.x) >> 6;
    int nw = gridDim.x * 4;
    const int NT = N_NODES / 16;           // 6250 row-tiles
    for (int tile = gw; tile < NT; tile += nw) {
        int r0 = tile * 16;
        size_t rowoff = (size_t)(r0 + c) * CH_F + (q & 1) * 8;
        // kh=0 -> chunks 0,1 ; kh=1 -> chunks 2,3 ; chunk = kh*2 + (q>>1)
        bf16x8 a0 = *(const bf16x8*)(cvb + (size_t)(q >> 1) * (N_NODES * CH_F) + rowoff);
        bf16x8 a1 = *(const bf16x8*)(cvb + (size_t)(2 + (q >> 1)) * (N_NODES * CH_F) + rowoff);
        #pragma unroll
        for (int t = 0; t < 4; ++t) {
            f32x4 acc = {0.f, 0.f, 0.f, 0.f};
            acc = __builtin_amdgcn_mfma_f32_16x16x32_bf16(a0, bf[t][0], acc, 0, 0, 0);
            acc = __builtin_amdgcn_mfma_f32_16x16x32_bf16(a1, bf[t][1], acc, 0, 0, 0);
            #pragma unroll
            for (int r = 0; r < 4; ++r) {
                float hv = acc[r] + bmv[t];
                h[(size_t)(r0 + q * 4 + r) * OUT_F + t * 16 + c] = hv;
                s[t]  += hv;
                s2[t] += hv * hv;
            }
        }
    }
    // reduce over quads (lanes sharing c): xor 16, 32
    #pragma unroll
    for (int t = 0; t < 4; ++t) {
        #pragma unroll
        for (int m = 16; m < 64; m <<= 1) {
            s[t]  += __shfl_xor(s[t],  m, 64);
            s2[t] += __shfl_xor(s2[t], m, 64);
        }
    }
    if (lane < 16) {
        #pragma unroll
        for (int t = 0; t < 4; ++t) {
            atomicAdd(&bns[t * 16 + lane], s[t]);
            atomicAdd(&bns[64 + t * 16 + lane], s2[t]);
        }
    }
}

// ---------------------------------------------------------------------------
// K8: BN normalize + LeakyReLU + residual (x @ W_res + b_res) + LeakyReLU
// ---------------------------------------------------------------------------
__global__ __launch_bounds__(256) void k_final(
    const float* __restrict__ x, const float* __restrict__ Wr,
    const float* __restrict__ br, const float* __restrict__ bns,
    const float* __restrict__ gamma, const float* __restrict__ beta,
    float* __restrict__ out)
{
    __shared__ float sWr[IN_F * OUT_F];
    for (int i = threadIdx.x; i < IN_F * OUT_F; i += 256) sWr[i] = Wr[i];
    __syncthreads();
    int wave = threadIdx.x >> 6;
    int lane = threadIdx.x & 63;
    int n = blockIdx.x * 4 + wave;
    const float inv_n = 1.f / (float)N_NODES;
    float mean = bns[lane] * inv_n;
    float var  = bns[64 + lane] * inv_n - mean * mean;
    float rstd = rsqrtf(var + BN_EPS);
    float g = gamma[lane], bt = beta[lane];

    const float* xr = x + n * IN_F;
    float r = br[lane];
    #pragma unroll
    for (int k = 0; k < IN_F; ++k) r += xr[k] * sWr[k * OUT_F + lane];

    float hv = out[(size_t)n * OUT_F + lane];
    float a = g * (hv - mean) * rstd + bt;
    a = (a >= 0.f) ? a : SLOPE * a;
    float y = a + r;
    out[(size_t)n * OUT_F + lane] = (y >= 0.f) ? y : SLOPE * y;
}

// ---------------------------------------------------------------------------
extern "C" void kernel_launch(void* const* d_in, const int* in_sizes, int n_in,
                              void* d_out, int out_size, void* d_ws, size_t ws_size,
                              hipStream_t stream) {
    const float* x     = (const float*)d_in[0];
    const int*   hidx  = (const int*)d_in[1];
    const int*   ni    = hidx;               // row 0: node idx
    const int*   ei    = hidx + P_PAIRS;     // row 1: edge idx
    const float* Wc    = (const float*)d_in[2];
    const float* bc    = (const float*)d_in[3];
    const float* Wm    = (const float*)d_in[4];
    const float* bm    = (const float*)d_in[5];
    const float* gamma = (const float*)d_in[6];
    const float* beta  = (const float*)d_in[7];
    const float* Wr    = (const float*)d_in[8];
    const float* br    = (const float*)d_in[9];
    float* out = (float*)d_out;

    // --- ws (~40 MB): [adjE P][adjN P][stage 391*9000 u32 / efb alias][bns 128f]
    int* adjE = (int*)d_ws;
    int* adjN = adjE + P_PAIRS;
    unsigned int* stage = (unsigned int*)(adjN + P_PAIRS);
    unsigned short* efb = (unsigned short*)stage;        // [4][N][16], stage dead by then
    float* bns = (float*)(stage + (size_t)BUCKETS * CAP);
    unsigned short* cvb = (unsigned short*)adjE;         // [4][N][16], adjE dead after hop1

    // --- d_out lower half: xwb [4][N][16] bf16 (dead before h); upper: small arrays
    unsigned short* xwb = (unsigned short*)d_out;
    int* smalls = (int*)(out + (size_t)N_NODES * OUT_F / 2);
    int* curE  = smalls;
    int* curN  = curE + BUCKETS;
    int* baseE = curN + BUCKETS;
    int* baseN = baseE + BUCKETS;
    int* offE  = baseN + BUCKETS;
    int* lenE  = offE + N_NODES;
    int* offN  = lenE + N_NODES;
    int* lenN  = offN + N_NODES;

    hipMemsetAsync(bns, 0, 128 * sizeof(float), stream);
    hipMemsetAsync(curE, 0, 2 * BUCKETS * sizeof(int), stream);

    k_input_gemm<<<N_NODES / 4, 256, 0, stream>>>(x, Wc, xwb);

    // edge-side CSR
    k_bucket1<<<P_PAIRS / CHUNK_P, 256, 0, stream>>>(ei, ni, curE, stage);
    k_minscan<<<1, 512, 0, stream>>>(curE, baseE);
    k_bucket2<<<BUCKETS, 256, 0, stream>>>(stage, curE, baseE, adjE, offE, lenE);
    // node-side CSR (stage reused)
    k_bucket1<<<P_PAIRS / CHUNK_P, 256, 0, stream>>>(ni, ei, curN, stage);
    k_minscan<<<1, 512, 0, stream>>>(curN, baseN);
    k_bucket2<<<BUCKETS, 256, 0, stream>>>(stage, curN, baseN, adjN, offN, lenN);

    // hop1: per-chunk L2-resident gathers (stage dead -> efb)
    for (int c = 0; c < NCH; ++c)
        k_hop1<<<N_NODES / 4, 256, 0, stream>>>(
            adjE, offE, lenE,
            xwb + (size_t)c * N_NODES * CH_F,
            efb + (size_t)c * N_NODES * CH_F);

    // hop2: per-chunk (adjE dead -> cvb)
    for (int c = 0; c < NCH; ++c)
        k_hop2<<<N_NODES / 4, 256, 0, stream>>>(
            adjN, offN, lenN,
            efb + (size_t)c * N_NODES * CH_F,
            cvb + (size_t)c * N_NODES * CH_F,
            bc + c * CH_F);

    k_mlp_mfma<<<512, 256, 0, stream>>>(cvb, Wm, bm, out, bns);
    k_final<<<N_NODES / 4, 256, 0, stream>>>(x, Wr, br, bns, gamma, beta, out);
}

// Round 7
// 585.306 us; speedup vs baseline: 3.4301x; 1.3896x over previous
//
#include <hip/hip_runtime.h>

#define N_NODES 100000
#define P_PAIRS 3200000
#define IN_F    19
#define OUT_F   64
#define BN_EPS  1e-5f
#define SLOPE   0.01f
#define BSHIFT  8       // 256 keys per bucket
#define BUCKETS 391     // ceil(N_NODES / 256)
#define CAP     9000    // staging capacity per bucket (mean 8184, sd ~90)
#define CHUNK_P 6400    // pairs per bucket1 block (P / 6400 = 500 blocks)
#define NCH     4       // channel chunks
#define CH_F    16      // channels per chunk (32 B rows, 3.2 MB table -> L2-resident)

typedef __attribute__((ext_vector_type(8))) unsigned short u16x8;
typedef __attribute__((ext_vector_type(8))) short bf16x8;
typedef __attribute__((ext_vector_type(4))) float f32x4;

__device__ __forceinline__ float bf2f(unsigned short h) {
    return __uint_as_float(((unsigned)h) << 16);
}
__device__ __forceinline__ unsigned short f2bf(float f) {
    unsigned u = __float_as_uint(f);
    return (unsigned short)((u + 0x7FFF + ((u >> 16) & 1)) >> 16);  // RNE
}

// ---------------------------------------------------------------------------
// K1: xw = x @ W_conv  -> bf16 chunk-major table [4][N][16] (in d_out lower half)
// ---------------------------------------------------------------------------
__global__ __launch_bounds__(256) void k_input_gemm(
    const float* __restrict__ x, const float* __restrict__ Wc,
    unsigned short* __restrict__ xwb)
{
    __shared__ float sWc[IN_F * OUT_F];
    for (int i = threadIdx.x; i < IN_F * OUT_F; i += 256) sWc[i] = Wc[i];
    __syncthreads();
    int wave = threadIdx.x >> 6;
    int lane = threadIdx.x & 63;
    int n = blockIdx.x * 4 + wave;           // N divisible by 4
    const float* xr = x + n * IN_F;
    float acc = 0.f;
    #pragma unroll
    for (int k = 0; k < IN_F; ++k) acc += xr[k] * sWc[k * OUT_F + lane];
    xwb[(size_t)(lane >> 4) * (N_NODES * CH_F) + (size_t)n * CH_F + (lane & 15)] = f2bf(acc);
}

// ---------------------------------------------------------------------------
// K2: bucket phase 1 — bin pairs into fixed-capacity per-bucket staging.
// stage entry: (key & 255) << 17 | value  (both ids < 2^17)
// ---------------------------------------------------------------------------
__global__ __launch_bounds__(256) void k_bucket1(
    const int* __restrict__ key, const int* __restrict__ val,
    int* __restrict__ cur, unsigned int* __restrict__ stage)
{
    __shared__ int hist[BUCKETS];
    __shared__ int base_s[BUCKETS];
    int t = threadIdx.x;
    for (int b = t; b < BUCKETS; b += 256) hist[b] = 0;
    __syncthreads();
    int p0 = blockIdx.x * CHUNK_P;
    for (int i = t; i < CHUNK_P; i += 256)
        atomicAdd(&hist[key[p0 + i] >> BSHIFT], 1);
    __syncthreads();
    for (int b = t; b < BUCKETS; b += 256) {
        int c = hist[b];
        base_s[b] = (c > 0) ? atomicAdd(&cur[b], c) : 0;
        hist[b] = 0;                      // reuse as local cursor
    }
    __syncthreads();
    for (int i = t; i < CHUNK_P; i += 256) {
        int k = key[p0 + i];
        int v = val[p0 + i];
        int bk = k >> BSHIFT;
        int pos = base_s[bk] + atomicAdd(&hist[bk], 1);
        if (pos < CAP)                    // 9-sigma guard; never expected
            stage[(size_t)bk * CAP + pos] = ((unsigned)(k & 255) << 17) | (unsigned)v;
    }
}

// ---------------------------------------------------------------------------
// K3: mini-scan of 391 bucket totals -> bucket base offsets
// ---------------------------------------------------------------------------
__global__ __launch_bounds__(512) void k_minscan(
    const int* __restrict__ cur, int* __restrict__ base)
{
    __shared__ int s[512];
    int t = threadIdx.x;
    int v = (t < BUCKETS) ? cur[t] : 0;
    s[t] = v;
    __syncthreads();
    for (int off = 1; off < 512; off <<= 1) {
        int tmp = (t >= off) ? s[t - off] : 0;
        __syncthreads();
        s[t] += tmp;
        __syncthreads();
    }
    if (t < BUCKETS) base[t] = s[t] - v;   // exclusive
}

// ---------------------------------------------------------------------------
// K4: bucket phase 2 — per-key count + in-block scan -> off/len, then place.
// ---------------------------------------------------------------------------
__global__ __launch_bounds__(256) void k_bucket2(
    const unsigned int* __restrict__ stage, const int* __restrict__ cur,
    const int* __restrict__ base, int* __restrict__ adj,
    int* __restrict__ offK, int* __restrict__ lenK)
{
    __shared__ int cnt[256];
    __shared__ int s[256];
    __shared__ int cur_l[256];
    int b = blockIdx.x;
    int t = threadIdx.x;
    int m = cur[b]; if (m > CAP) m = CAP;
    size_t sbase = (size_t)b * CAP;
    cnt[t] = 0;
    __syncthreads();
    for (int i = t; i < m; i += 256)
        atomicAdd(&cnt[stage[sbase + i] >> 17], 1);
    __syncthreads();
    int c = cnt[t];
    s[t] = c;
    __syncthreads();
    for (int off = 1; off < 256; off <<= 1) {
        int tmp = (t >= off) ? s[t - off] : 0;
        __syncthreads();
        s[t] += tmp;
        __syncthreads();
    }
    int keyoff = base[b] + s[t] - c;       // global exclusive offset for key
    int k = (b << BSHIFT) + t;
    if (k < N_NODES) { offK[k] = keyoff; lenK[k] = c; }
    cur_l[t] = keyoff;
    __syncthreads();
    for (int i = t; i < m; i += 256) {
        unsigned v = stage[sbase + i];
        int kl = v >> 17;
        int pos = atomicAdd(&cur_l[kl], 1);
        adj[pos] = (int)(v & 0x1FFFF);
    }
}

// ---------------------------------------------------------------------------
// K5: hop, one channel chunk, generic: out_c[k] = scale * sum in_c[adj[seg(k)]]
// 4 segments per wave: lane = (seg-slot 2b, row-slot 3b, chan-half 1b)
// 3-round shfl reduce; bias added via bcc (nullptr for hop1).
// ---------------------------------------------------------------------------
__global__ __launch_bounds__(256) void k_hop(
    const int* __restrict__ adj, const int* __restrict__ offK,
    const int* __restrict__ lenK, const unsigned short* __restrict__ tin,
    unsigned short* __restrict__ tout, const float* __restrict__ bcc)
{
    int lane = threadIdx.x & 63;
    int wv = threadIdx.x >> 6;
    int es  = lane >> 4;                   // segment slot 0..3
    int sub = (lane >> 1) & 7;             // row slot 0..7
    int cg  = lane & 1;                    // 8-chan half
    int k = (blockIdx.x * 4 + wv) * 4 + es;  // grid = N/16
    int len = lenK[k];
    int start = offK[k];
    int end = start + len;

    float acc[8];
    #pragma unroll
    for (int j = 0; j < 8; ++j) acc[j] = 0.f;

    for (int i = start + sub; i < end; i += 8) {
        int idx = __builtin_nontemporal_load(&adj[i]);
        u16x8 v = *(const u16x8*)(tin + (size_t)idx * CH_F + cg * 8);
        #pragma unroll
        for (int j = 0; j < 8; ++j) acc[j] += bf2f(v[j]);
    }
    #pragma unroll
    for (int m = 2; m < 16; m <<= 1) {     // reduce over sub (lane bits 1..3)
        #pragma unroll
        for (int j = 0; j < 8; ++j) acc[j] += __shfl_xor(acc[j], m, 64);
    }
    if ((lane & 14) == 0) {                // sub == 0
        float sc = (len > 0) ? 1.f / (float)len : 0.f;
        u16x8 o;
        if (bcc) {
            #pragma unroll
            for (int j = 0; j < 8; ++j) o[j] = f2bf(acc[j] * sc + bcc[cg * 8 + j]);
        } else {
            #pragma unroll
            for (int j = 0; j < 8; ++j) o[j] = f2bf(acc[j] * sc);
        }
        __builtin_nontemporal_store(o, (u16x8*)(tout + (size_t)k * CH_F + cg * 8));
    }
}

// ---------------------------------------------------------------------------
// K6: MLP via MFMA: h = cv @ Wm + bm  (+ BN partials, block-reduced in LDS)
// one wave per 16-node row-tile; A = cv (bf16, chunk-major), B = Wm in regs.
// mfma_f32_16x16x32_bf16: A[m=lane&15][k=quad*8+j]; D: col=lane&15,
// row=quad*4+reg. Chunk-major cv maps A's k-seg to one contiguous load.
// ---------------------------------------------------------------------------
__global__ __launch_bounds__(256) void k_mlp_mfma(
    const unsigned short* __restrict__ cvb, const float* __restrict__ Wm,
    const float* __restrict__ bm, float* __restrict__ h,
    float* __restrict__ bns)
{
    __shared__ float red[128];             // [sum 64][sumsq 64]
    if (threadIdx.x < 128) red[threadIdx.x] = 0.f;
    __syncthreads();

    int lane = threadIdx.x & 63;
    int q = lane >> 4;                     // quad: k-segment / D row group
    int c = lane & 15;                     // A row / D col (within tile)

    // B fragments: 4 col-tiles x 2 k-halves; B[k=kh*32+q*8+j][col=t*16+c]
    bf16x8 bf[4][2];
    #pragma unroll
    for (int t = 0; t < 4; ++t)
        #pragma unroll
        for (int kh = 0; kh < 2; ++kh)
            #pragma unroll
            for (int j = 0; j < 8; ++j)
                bf[t][kh][j] = (short)f2bf(Wm[(kh * 32 + q * 8 + j) * OUT_F + t * 16 + c]);
    float bmv[4];
    #pragma unroll
    for (int t = 0; t < 4; ++t) bmv[t] = bm[t * 16 + c];

    float s[4], s2[4];
    #pragma unroll
    for (int t = 0; t < 4; ++t) { s[t] = 0.f; s2[t] = 0.f; }

    int gw = (blockIdx.x * 256 + threadIdx.x) >> 6;
    int nw = gridDim.x * 4;
    const int NT = N_NODES / 16;           // 6250 row-tiles
    for (int tile = gw; tile < NT; tile += nw) {
        int r0 = tile * 16;
        size_t rowoff = (size_t)(r0 + c) * CH_F + (q & 1) * 8;
        // kh=0 -> chunks 0,1 ; kh=1 -> chunks 2,3 ; chunk = kh*2 + (q>>1)
        bf16x8 a0 = *(const bf16x8*)(cvb + (size_t)(q >> 1) * (N_NODES * CH_F) + rowoff);
        bf16x8 a1 = *(const bf16x8*)(cvb + (size_t)(2 + (q >> 1)) * (N_NODES * CH_F) + rowoff);
        #pragma unroll
        for (int t = 0; t < 4; ++t) {
            f32x4 acc = {0.f, 0.f, 0.f, 0.f};
            acc = __builtin_amdgcn_mfma_f32_16x16x32_bf16(a0, bf[t][0], acc, 0, 0, 0);
            acc = __builtin_amdgcn_mfma_f32_16x16x32_bf16(a1, bf[t][1], acc, 0, 0, 0);
            #pragma unroll
            for (int r = 0; r < 4; ++r) {
                float hv = acc[r] + bmv[t];
                h[(size_t)(r0 + q * 4 + r) * OUT_F + t * 16 + c] = hv;
                s[t]  += hv;
                s2[t] += hv * hv;
            }
        }
    }
    // reduce over quads (lanes sharing c): xor 16, 32
    #pragma unroll
    for (int t = 0; t < 4; ++t) {
        #pragma unroll
        for (int m = 16; m < 64; m <<= 1) {
            s[t]  += __shfl_xor(s[t],  m, 64);
            s2[t] += __shfl_xor(s2[t], m, 64);
        }
    }
    if (lane < 16) {
        #pragma unroll
        for (int t = 0; t < 4; ++t) {
            atomicAdd(&red[t * 16 + lane], s[t]);
            atomicAdd(&red[64 + t * 16 + lane], s2[t]);
        }
    }
    __syncthreads();
    if (threadIdx.x < 128) atomicAdd(&bns[threadIdx.x], red[threadIdx.x]);
}

// ---------------------------------------------------------------------------
// K7: BN normalize + LeakyReLU + residual (x @ W_res + b_res) + LeakyReLU
// ---------------------------------------------------------------------------
__global__ __launch_bounds__(256) void k_final(
    const float* __restrict__ x, const float* __restrict__ Wr,
    const float* __restrict__ br, const float* __restrict__ bns,
    const float* __restrict__ gamma, const float* __restrict__ beta,
    float* __restrict__ out)
{
    __shared__ float sWr[IN_F * OUT_F];
    for (int i = threadIdx.x; i < IN_F * OUT_F; i += 256) sWr[i] = Wr[i];
    __syncthreads();
    int wave = threadIdx.x >> 6;
    int lane = threadIdx.x & 63;
    int n = blockIdx.x * 4 + wave;
    const float inv_n = 1.f / (float)N_NODES;
    float mean = bns[lane] * inv_n;
    float var  = bns[64 + lane] * inv_n - mean * mean;
    float rstd = rsqrtf(var + BN_EPS);
    float g = gamma[lane], bt = beta[lane];

    const float* xr = x + n * IN_F;
    float r = br[lane];
    #pragma unroll
    for (int k = 0; k < IN_F; ++k) r += xr[k] * sWr[k * OUT_F + lane];

    float hv = out[(size_t)n * OUT_F + lane];
    float a = g * (hv - mean) * rstd + bt;
    a = (a >= 0.f) ? a : SLOPE * a;
    float y = a + r;
    out[(size_t)n * OUT_F + lane] = (y >= 0.f) ? y : SLOPE * y;
}

// ---------------------------------------------------------------------------
extern "C" void kernel_launch(void* const* d_in, const int* in_sizes, int n_in,
                              void* d_out, int out_size, void* d_ws, size_t ws_size,
                              hipStream_t stream) {
    const float* x     = (const float*)d_in[0];
    const int*   hidx  = (const int*)d_in[1];
    const int*   ni    = hidx;               // row 0: node idx
    const int*   ei    = hidx + P_PAIRS;     // row 1: edge idx
    const float* Wc    = (const float*)d_in[2];
    const float* bc    = (const float*)d_in[3];
    const float* Wm    = (const float*)d_in[4];
    const float* bm    = (const float*)d_in[5];
    const float* gamma = (const float*)d_in[6];
    const float* beta  = (const float*)d_in[7];
    const float* Wr    = (const float*)d_in[8];
    const float* br    = (const float*)d_in[9];
    float* out = (float*)d_out;

    // --- ws (~40 MB): [adjE P][adjN P][stage 391*9000 u32 / efb alias][bns 128f]
    int* adjE = (int*)d_ws;
    int* adjN = adjE + P_PAIRS;
    unsigned int* stage = (unsigned int*)(adjN + P_PAIRS);
    unsigned short* efb = (unsigned short*)stage;        // [4][N][16], stage dead by then
    float* bns = (float*)(stage + (size_t)BUCKETS * CAP);
    unsigned short* cvb = (unsigned short*)adjE;         // [4][N][16], adjE dead after hop1

    // --- d_out lower half: xwb [4][N][16] bf16 (dead before h); upper: small arrays
    unsigned short* xwb = (unsigned short*)d_out;
    int* smalls = (int*)(out + (size_t)N_NODES * OUT_F / 2);
    int* curE  = smalls;
    int* curN  = curE + BUCKETS;
    int* baseE = curN + BUCKETS;
    int* baseN = baseE + BUCKETS;
    int* offE  = baseN + BUCKETS;
    int* lenE  = offE + N_NODES;
    int* offN  = lenE + N_NODES;
    int* lenN  = offN + N_NODES;

    hipMemsetAsync(bns, 0, 128 * sizeof(float), stream);
    hipMemsetAsync(curE, 0, 2 * BUCKETS * sizeof(int), stream);

    k_input_gemm<<<N_NODES / 4, 256, 0, stream>>>(x, Wc, xwb);

    // edge-side CSR
    k_bucket1<<<P_PAIRS / CHUNK_P, 256, 0, stream>>>(ei, ni, curE, stage);
    k_minscan<<<1, 512, 0, stream>>>(curE, baseE);
    k_bucket2<<<BUCKETS, 256, 0, stream>>>(stage, curE, baseE, adjE, offE, lenE);
    // node-side CSR (stage reused)
    k_bucket1<<<P_PAIRS / CHUNK_P, 256, 0, stream>>>(ni, ei, curN, stage);
    k_minscan<<<1, 512, 0, stream>>>(curN, baseN);
    k_bucket2<<<BUCKETS, 256, 0, stream>>>(stage, curN, baseN, adjN, offN, lenN);

    // hop1: per-chunk L2-resident gathers (stage dead -> efb)
    for (int c = 0; c < NCH; ++c)
        k_hop<<<N_NODES / 16, 256, 0, stream>>>(
            adjE, offE, lenE,
            xwb + (size_t)c * N_NODES * CH_F,
            efb + (size_t)c * N_NODES * CH_F,
            (const float*)nullptr);

    // hop2: per-chunk (adjE dead -> cvb)
    for (int c = 0; c < NCH; ++c)
        k_hop<<<N_NODES / 16, 256, 0, stream>>>(
            adjN, offN, lenN,
            efb + (size_t)c * N_NODES * CH_F,
            cvb + (size_t)c * N_NODES * CH_F,
            bc + c * CH_F);

    k_mlp_mfma<<<256, 256, 0, stream>>>(cvb, Wm, bm, out, bns);
    k_final<<<N_NODES / 4, 256, 0, stream>>>(x, Wr, br, bns, gamma, beta, out);
}